// Round 5
// baseline (625.720 us; speedup 1.0000x reference)
//
#include <hip/hip_runtime.h>
#include <cstdint>

// ChessRelativeTransformer on MI355X (gfx950), bf16 MFMA pipeline.
// B=512 T=64 H=16 DH=64 D=1024 NUM_REL=225 scale=0.125
// R5: stage-order swap (P1 stages A0[o] -- the soonest-consumed half -- and
//     P2 stages B1[o]) + retuned counted waits {P2:8, P4:6, P6:8, P8:6} so
//     every vmcnt's newest-drained load has 3-4 phases of slack (was 2).
//     Full ledger traced in commit message; epilogue drains 8->2->0.

typedef unsigned short u16;
typedef unsigned int u32;
typedef __bf16 bf16x8 __attribute__((ext_vector_type(8)));
typedef float f32x4 __attribute__((ext_vector_type(4)));

#define MFMA16(a, b, c) __builtin_amdgcn_mfma_f32_16x16x32_bf16(a, b, c, 0, 0, 0)

__device__ __forceinline__ u16 f2bf(float f) {
  u32 u = __builtin_bit_cast(u32, f);
  u = (u + 0x7FFFu + ((u >> 16) & 1u)) >> 16;
  return (u16)u;
}
__device__ __forceinline__ float bf2f(u16 h) {
  return __builtin_bit_cast(float, ((u32)h) << 16);
}

__device__ __forceinline__ void g2l16(const void* g, void* lds_wave_base) {
#if __has_builtin(__builtin_amdgcn_global_load_lds)
  __builtin_amdgcn_global_load_lds(
      (const __attribute__((address_space(1))) u32*)(uintptr_t)g,
      (__attribute__((address_space(3))) u32*)(uintptr_t)lds_wave_base, 16, 0, 0);
#else
  uint4 v = *(const uint4*)g;
  *(uint4*)((char*)lds_wave_base + (threadIdx.x & 63) * 16) = v;
#endif
}

// ---------------- fp32 -> bf16 convert (4 elems/thread) ----------------
__global__ __launch_bounds__(256) void k_cvt(const float* __restrict__ src,
                                             u16* __restrict__ dst, int nq) {
  int i = blockIdx.x * 256 + threadIdx.x;
  if (i >= nq) return;
  float4 v = ((const float4*)src)[i];
  ushort4 o;
  o.x = f2bf(v.x); o.y = f2bf(v.y); o.z = f2bf(v.z); o.w = f2bf(v.w);
  ((ushort4*)dst)[i] = o;
}

// ================= 256x256 8-phase GEMM core (R5 schedule) =================
// C = A * Bm^T. 512 thr = 8 waves (2M x 4N), BK=64, 128KiB dbuf LDS.
// Stage schedule per iteration (tiles e=2u buf0, o=2u+1 buf1):
//  P1(e,q00) rd A0,B0 | st A0[o]          (read P5: 3-4 ph slack)
//  P2(e,q10) rd A1    | st B1[o]  vm(8)   (drains B1[e], issued prev P6: 4ph)
//  P3(e,q11) rd B1    | st B0[e+2]
//  P4(e,q01) --       | st A1[e+2] vm(6)  (drains ...,A0[o] issued P1: 3ph)
//  P5(o,q00) rd A0,B0 | st A0[e+2]
//  P6(o,q10) rd A1    | st B1[e+2] vm(8)  (drains B1[o] issued P2: 4ph)
//  P7(o,q11) rd B1    | st B0[o+2]
//  P8(o,q01) --       | st A1[o+2] vm(6)  (drains ...,A0[e+2] issued P5: 3ph)
// Steady entry queue = [B1[e], B0[o], A1[o]] (6 loads). Prologue: 6 halves,
// vmcnt(4). Peeled last iter: stage A0[15]@P1, B1[15]@P2; waits 8,2,0.

__device__ __forceinline__ void stageA(const u16* __restrict__ A, int row0,
                                       int kb, char* lds, int buf, int half,
                                       int tid) {
#pragma unroll
  for (int g = 0; g < 2; g++) {
    int ch = g * 512 + tid;
    int sub = ch >> 3, sl = ch & 7;
    int R = (sub & 63) | (half << 6) | ((sub & 64) << 1);
    int kg = sl ^ (sub & 7);
    g2l16(A + (size_t)(row0 + R) * 1024 + kb + kg * 8,
          lds + (buf * 2 + half) * 16384 + g * 8192 + (tid >> 6) * 1024);
  }
}
__device__ __forceinline__ void stageB(const u16* __restrict__ Bm, int col0,
                                       int kb, char* lds, int buf, int half,
                                       int tid) {
#pragma unroll
  for (int g = 0; g < 2; g++) {
    int ch = g * 512 + tid;
    int sub = ch >> 3, sl = ch & 7;
    int C = (sub & 31) | (half << 5) | ((sub & 0x60) << 1);
    int kg = sl ^ (sub & 7);
    g2l16(Bm + (size_t)(col0 + C) * 1024 + kb + kg * 8,
          lds + 65536 + (buf * 2 + half) * 16384 + g * 8192 + (tid >> 6) * 1024);
  }
}

// RA: 0 none, 1 -> afA, 2 -> afC.  RB: 0 none, 1 -> bfB.  USEA: 0 afA, 1 afC.
// SMAT: 0 stage A, 1 stage B. VMn: -1 none, else vmcnt value.
template <int MH, int NH, int RA, int RB, int USEA, int SMAT, int SHALF,
          int SBUF, int KADD, int VMn>
__device__ __forceinline__ void phz(const u16* __restrict__ A,
                                    const u16* __restrict__ Bm, int row0,
                                    int col0, int k0, char* lds, int cbuf,
                                    f32x4 (&acc)[8][4], bf16x8 (&afA)[4][2],
                                    bf16x8 (&afC)[4][2], bf16x8 (&bfB)[2][2],
                                    int wr, int wc, int l15, int l4, int tid,
                                    bool st) {
  if (RA) {
#pragma unroll
    for (int m = 0; m < 4; m++) {
      int sub = wr * 64 + m * 16 + l15;
      const char* p = lds + (cbuf * 2 + MH) * 16384 + sub * 128;
#pragma unroll
      for (int kk = 0; kk < 2; kk++) {
        bf16x8 v = *(const bf16x8*)(p + (((kk * 4 + l4) ^ (sub & 7)) << 4));
        if (RA == 1) afA[m][kk] = v; else afC[m][kk] = v;
      }
    }
  }
  if (RB) {
#pragma unroll
    for (int n = 0; n < 2; n++) {
      int sub = wc * 32 + n * 16 + l15;
      const char* p = lds + 65536 + (cbuf * 2 + NH) * 16384 + sub * 128;
#pragma unroll
      for (int kk = 0; kk < 2; kk++)
        bfB[n][kk] = *(const bf16x8*)(p + (((kk * 4 + l4) ^ (sub & 7)) << 4));
    }
  }
  if (st) {
    if (SMAT == 0)
      stageA(A, row0, k0 + KADD * 64, lds, SBUF, SHALF, tid);
    else
      stageB(Bm, col0, k0 + KADD * 64, lds, SBUF, SHALF, tid);
  }
  __builtin_amdgcn_s_barrier();
  asm volatile("s_waitcnt lgkmcnt(0)" ::: "memory");
  __builtin_amdgcn_sched_barrier(0);
  __builtin_amdgcn_s_setprio(1);
#pragma unroll
  for (int m = 0; m < 4; m++)
#pragma unroll
    for (int n = 0; n < 2; n++)
#pragma unroll
      for (int kk = 0; kk < 2; kk++)
        acc[MH * 4 + m][NH * 2 + n] = MFMA16(USEA ? afC[m][kk] : afA[m][kk],
                                             bfB[n][kk],
                                             acc[MH * 4 + m][NH * 2 + n]);
  __builtin_amdgcn_s_setprio(0);
  if constexpr (VMn == 8) asm volatile("s_waitcnt vmcnt(8)" ::: "memory");
  else if constexpr (VMn == 6) asm volatile("s_waitcnt vmcnt(6)" ::: "memory");
  else if constexpr (VMn == 4) asm volatile("s_waitcnt vmcnt(4)" ::: "memory");
  else if constexpr (VMn == 2) asm volatile("s_waitcnt vmcnt(2)" ::: "memory");
  else if constexpr (VMn == 0) asm volatile("s_waitcnt vmcnt(0)" ::: "memory");
  __builtin_amdgcn_s_barrier();
}

__device__ __forceinline__ void gemm256_core(const u16* __restrict__ A,
                                             const u16* __restrict__ Bm,
                                             int row0, int col0, char* lds,
                                             f32x4 (&acc)[8][4], int tid) {
  const int lane = tid & 63, w = tid >> 6;
  const int wr = w >> 2, wc = w & 3;
  const int l15 = lane & 15, l4 = lane >> 4;
  bf16x8 afA[4][2], afC[4][2], bfB[2][2];
  // prologue: tile0 all 4 halves (buf0) + tile1 B0,A1 (buf1); drain tile0.
  stageA(A, row0, 0, lds, 0, 0, tid);
  stageB(Bm, col0, 0, lds, 0, 0, tid);
  stageA(A, row0, 0, lds, 0, 1, tid);
  stageB(Bm, col0, 0, lds, 0, 1, tid);
  stageB(Bm, col0, 64, lds, 1, 0, tid);
  stageA(A, row0, 64, lds, 1, 1, tid);
  asm volatile("s_waitcnt vmcnt(4)" ::: "memory");
  __builtin_amdgcn_s_barrier();
  for (int u = 0; u < 7; ++u) {
    int k0 = u * 128;
    phz<0,0,1,1,0, 0,0,1,1,-1>(A,Bm,row0,col0,k0,lds,0,acc,afA,afC,bfB,wr,wc,l15,l4,tid,true);
    phz<1,0,2,0,1, 1,1,1,1, 8>(A,Bm,row0,col0,k0,lds,0,acc,afA,afC,bfB,wr,wc,l15,l4,tid,true);
    phz<1,1,0,1,1, 1,0,0,2,-1>(A,Bm,row0,col0,k0,lds,0,acc,afA,afC,bfB,wr,wc,l15,l4,tid,true);
    phz<0,1,0,0,0, 0,1,0,2, 6>(A,Bm,row0,col0,k0,lds,0,acc,afA,afC,bfB,wr,wc,l15,l4,tid,true);
    phz<0,0,1,1,0, 0,0,0,2,-1>(A,Bm,row0,col0,k0,lds,1,acc,afA,afC,bfB,wr,wc,l15,l4,tid,true);
    phz<1,0,2,0,1, 1,1,0,2, 8>(A,Bm,row0,col0,k0,lds,1,acc,afA,afC,bfB,wr,wc,l15,l4,tid,true);
    phz<1,1,0,1,1, 1,0,1,3,-1>(A,Bm,row0,col0,k0,lds,1,acc,afA,afC,bfB,wr,wc,l15,l4,tid,true);
    phz<0,1,0,0,0, 0,1,1,3, 6>(A,Bm,row0,col0,k0,lds,1,acc,afA,afC,bfB,wr,wc,l15,l4,tid,true);
  }
  {  // peeled final iteration (tiles 14,15): stage A0[15]@P1, B1[15]@P2;
     // drains: P2 vm(8), P4 vm(2), P6 vm(0).
    const int k0 = 896;
    phz<0,0,1,1,0, 0,0,1,1,-1>(A,Bm,row0,col0,k0,lds,0,acc,afA,afC,bfB,wr,wc,l15,l4,tid,true);
    phz<1,0,2,0,1, 1,1,1,1, 8>(A,Bm,row0,col0,k0,lds,0,acc,afA,afC,bfB,wr,wc,l15,l4,tid,true);
    phz<1,1,0,1,1, 0,0,0,0,-1>(A,Bm,row0,col0,k0,lds,0,acc,afA,afC,bfB,wr,wc,l15,l4,tid,false);
    phz<0,1,0,0,0, 0,0,0,0, 2>(A,Bm,row0,col0,k0,lds,0,acc,afA,afC,bfB,wr,wc,l15,l4,tid,false);
    phz<0,0,1,1,0, 0,0,0,0,-1>(A,Bm,row0,col0,k0,lds,1,acc,afA,afC,bfB,wr,wc,l15,l4,tid,false);
    phz<1,0,2,0,1, 0,0,0,0, 0>(A,Bm,row0,col0,k0,lds,1,acc,afA,afC,bfB,wr,wc,l15,l4,tid,false);
    phz<1,1,0,1,1, 0,0,0,0,-1>(A,Bm,row0,col0,k0,lds,1,acc,afA,afC,bfB,wr,wc,l15,l4,tid,false);
    phz<0,1,0,0,0, 0,0,0,0,-1>(A,Bm,row0,col0,k0,lds,1,acc,afA,afC,bfB,wr,wc,l15,l4,tid,false);
  }
}

// ---------------- QKV GEMM: [32768x1024] x [3072x1024]^T ----------------
__global__ __launch_bounds__(512, 2) void k_gemm_qkv(
    const u16* __restrict__ A, const u16* __restrict__ Bm,
    const float* __restrict__ bq, const float* __restrict__ bk,
    const float* __restrict__ bv, u16* __restrict__ Qb, u16* __restrict__ Kb,
    u16* __restrict__ Vb) {
  __shared__ char lds[131072];
  const int tid = threadIdx.x;
  const int lane = tid & 63, w = tid >> 6;
  const int wr = w >> 2, wc = w & 3;
  const int l15 = lane & 15, l4 = lane >> 4;
  // XCD chunks of 192, col-fastest within: A-slab reused 12x consecutively
  int f = blockIdx.x;
  int swz = (f & 7) * 192 + (f >> 3);
  int bcol = swz % 12, brow = swz / 12;
  const int row0 = brow * 256, col0 = bcol * 256;
  f32x4 acc[8][4] = {};
  gemm256_core(A, Bm, row0, col0, lds, acc, tid);
#pragma unroll
  for (int nf = 0; nf < 4; nf++) {
    int col = col0 + wc * 64 + nf * 16 + l15;
    int sel = col >> 10, hd = col & 1023;
    int h = hd >> 6, d = hd & 63;
    const float* bp = (sel == 0) ? bq : (sel == 1) ? bk : bv;
    float bias = bp[hd];
    u16* dst = (sel == 0) ? Qb : (sel == 1) ? Kb : Vb;
#pragma unroll
    for (int mf = 0; mf < 8; mf++) {
      int rowb = row0 + wr * 128 + mf * 16 + l4 * 4;
#pragma unroll
      for (int j = 0; j < 4; j++) {
        int row = rowb + j;
        int b = row >> 6, t = row & 63;
        dst[((size_t)(b * 16 + h)) * 4096 + t * 64 + d] =
            f2bf(acc[mf][nf][j] + bias);
      }
    }
  }
}

// ---------------- output GEMM: [32768x1024] x [1024x1024]^T + bias -> fp32 --
__global__ __launch_bounds__(512, 2) void k_gemm_out(
    const u16* __restrict__ A, const u16* __restrict__ Bm,
    const float* __restrict__ bo, float* __restrict__ out) {
  __shared__ char lds[131072];
  const int tid = threadIdx.x;
  const int lane = tid & 63, w = tid >> 6;
  const int wr = w >> 2, wc = w & 3;
  const int l15 = lane & 15, l4 = lane >> 4;
  int f = blockIdx.x;  // 512 blocks = 8 chunks of 64, col-fastest
  int swz = (f & 7) * 64 + (f >> 3);
  int bcol = swz & 3, brow = swz >> 2;
  const int row0 = brow * 256, col0 = bcol * 256;
  f32x4 acc[8][4] = {};
  gemm256_core(A, Bm, row0, col0, lds, acc, tid);
#pragma unroll
  for (int nf = 0; nf < 4; nf++) {
    int col = col0 + wc * 64 + nf * 16 + l15;
    float bias = bo[col];
#pragma unroll
    for (int mf = 0; mf < 8; mf++) {
      int rowb = row0 + wr * 128 + mf * 16 + l4 * 4;
#pragma unroll
      for (int j = 0; j < 4; j++)
        out[(size_t)(rowb + j) * 1024 + col] = acc[mf][nf][j] + bias;
    }
  }
}

// ---------------- bias1[b,h,t,s] = sum_d q[b,h,t,d]*rel_k[h,idx[t,s],d] + T3
__global__ __launch_bounds__(256) void k_bias1(
    const u16* __restrict__ Qb, const u16* __restrict__ relq,
    const u16* __restrict__ relk, const int* __restrict__ relidx,
    u16* __restrict__ bias1) {
  const int tid = threadIdx.x, lane = tid & 63, w = tid >> 6;
  const int l15 = lane & 15, l4 = lane >> 4;
  const int t = blockIdx.x, h = blockIdx.y, bc = blockIdx.z;
  __shared__ char lds[16640];
  char* RK = lds;
  char* RQ = lds + 8192;
  float* T3 = (float*)(lds + 16384);
#pragma unroll
  for (int c = 0; c < 2; c++) {
    int ch = c * 256 + tid;
    int sr = ch >> 3, sl = (ch & 7) ^ (sr & 7);
    int ri = relidx[t * 64 + sr];
    size_t so = ((size_t)h * 225 + ri) * 64 + sl * 8;
    g2l16(relk + so, RK + c * 4096 + w * 1024);
    g2l16(relq + so, RQ + c * 4096 + w * 1024);
  }
  __syncthreads();
  if (tid < 64) {
    int sr = tid;
    float sum = 0.f;
#pragma unroll
    for (int sl = 0; sl < 8; sl++) {
      int o = sr * 128 + ((sl ^ (sr & 7)) << 4);
      bf16x8 aq = *(const bf16x8*)(RQ + o);
      bf16x8 ak = *(const bf16x8*)(RK + o);
#pragma unroll
      for (int j = 0; j < 8; j++) sum += (float)aq[j] * (float)ak[j];
    }
    T3[sr] = sum;
  }
  bf16x8 bfr[4][2];
#pragma unroll
  for (int n = 0; n < 4; n++)
#pragma unroll
    for (int kh = 0; kh < 2; kh++) {
      int r = n * 16 + l15;
      int sl = ((kh << 2) + l4) ^ (r & 7);
      bfr[n][kh] = *(const bf16x8*)(RK + r * 128 + sl * 16);
    }
  __syncthreads();
  f32x4 acc[4][4] = {};
#pragma unroll
  for (int m = 0; m < 4; m++) {
    int bb = bc * 256 + w * 64 + m * 16 + l15;
    const u16* ap = Qb + ((size_t)(bb * 16 + h)) * 4096 + t * 64 + l4 * 8;
    bf16x8 a0 = *(const bf16x8*)ap;
    bf16x8 a1 = *(const bf16x8*)(ap + 32);
#pragma unroll
    for (int n = 0; n < 4; n++) {
      acc[m][n] = MFMA16(a0, bfr[n][0], acc[m][n]);
      acc[m][n] = MFMA16(a1, bfr[n][1], acc[m][n]);
    }
  }
#pragma unroll
  for (int m = 0; m < 4; m++)
#pragma unroll
    for (int n = 0; n < 4; n++)
#pragma unroll
      for (int j = 0; j < 4; j++) {
        int bb = bc * 256 + w * 64 + m * 16 + l4 * 4 + j;
        int s_ = n * 16 + l15;
        bias1[((size_t)(bb * 16 + h)) * 4096 + t * 64 + s_] =
            f2bf(acc[m][n][j] + T3[s_]);
      }
}

// ---------------- bias2[b,h,s,t] = sum_d rel_q[h,idx[t,s],d]*k[b,h,s,d]
__global__ __launch_bounds__(256) void k_bias2(
    const u16* __restrict__ Kb, const u16* __restrict__ relq,
    const int* __restrict__ relidx, u16* __restrict__ bias2) {
  const int tid = threadIdx.x, lane = tid & 63, w = tid >> 6;
  const int l15 = lane & 15, l4 = lane >> 4;
  const int s = blockIdx.x, h = blockIdx.y, bc = blockIdx.z;
  __shared__ char lds[8192];
#pragma unroll
  for (int c = 0; c < 2; c++) {
    int ch = c * 256 + tid;
    int tq = ch >> 3, sl = (ch & 7) ^ (tq & 7);
    int ri = relidx[tq * 64 + s];
    g2l16(relq + ((size_t)h * 225 + ri) * 64 + sl * 8,
          lds + c * 4096 + w * 1024);
  }
  __syncthreads();
  bf16x8 bfr[4][2];
#pragma unroll
  for (int n = 0; n < 4; n++)
#pragma unroll
    for (int kh = 0; kh < 2; kh++) {
      int r = n * 16 + l15;
      int sl = ((kh << 2) + l4) ^ (r & 7);
      bfr[n][kh] = *(const bf16x8*)(lds + r * 128 + sl * 16);
    }
  f32x4 acc[4][4] = {};
#pragma unroll
  for (int m = 0; m < 4; m++) {
    int bb = bc * 256 + w * 64 + m * 16 + l15;
    const u16* ap = Kb + ((size_t)(bb * 16 + h)) * 4096 + s * 64 + l4 * 8;
    bf16x8 a0 = *(const bf16x8*)ap;
    bf16x8 a1 = *(const bf16x8*)(ap + 32);
#pragma unroll
    for (int n = 0; n < 4; n++) {
      acc[m][n] = MFMA16(a0, bfr[n][0], acc[m][n]);
      acc[m][n] = MFMA16(a1, bfr[n][1], acc[m][n]);
    }
  }
#pragma unroll
  for (int m = 0; m < 4; m++)
#pragma unroll
    for (int n = 0; n < 4; n++)
#pragma unroll
      for (int j = 0; j < 4; j++) {
        int bb = bc * 256 + w * 64 + m * 16 + l4 * 4 + j;
        int tcol = n * 16 + l15;
        bias2[((size_t)(bb * 16 + h)) * 4096 + s * 64 + tcol] =
            f2bf(acc[m][n][j]);
      }
}

// ---------------- attention per (b,h): S=QK^T + b1 + b2^T, softmax, P, PV ----
__global__ __launch_bounds__(256) void k_attn(
    const u16* __restrict__ Qb, const u16* __restrict__ Kb,
    const u16* __restrict__ Vb, const u16* __restrict__ b1g,
    const u16* __restrict__ b2g, u16* __restrict__ Pg,
    u16* __restrict__ aout) {
  const int tid = threadIdx.x, lane = tid & 63, w = tid >> 6;
  const int l15 = lane & 15, l4 = lane >> 4;
  const int b = blockIdx.x, h = blockIdx.y;
  __shared__ char lds[49152];
  char* Qt = lds;
  char* Kt = lds + 8192;
  char* Vt = lds + 16384;  // natural [s][d] layout
  char* B1 = lds + 24576;
  char* B2 = lds + 32768;
  char* Pt = lds + 40960;
  const size_t base = ((size_t)(b * 16 + h)) * 4096;
#pragma unroll
  for (int c = 0; c < 2; c++) {
    int ch = c * 256 + tid;
    int r = ch >> 3, sl = (ch & 7) ^ (r & 7);
    size_t so = base + r * 64 + sl * 8;
    int dst = c * 4096 + w * 1024;
    g2l16(Qb + so, Qt + dst);
    g2l16(Kb + so, Kt + dst);
    g2l16(Vb + so, Vt + dst);
    g2l16(b1g + so, B1 + dst);
    g2l16(b2g + so, B2 + dst);
  }
  __syncthreads();
  // S = Q K^T, wave w owns rows [w*16, w*16+16)
  f32x4 acc[4] = {};
  bf16x8 qf[2];
  {
    int r = w * 16 + l15;
#pragma unroll
    for (int kh = 0; kh < 2; kh++) {
      int sl = ((kh << 2) + l4) ^ (r & 7);
      qf[kh] = *(const bf16x8*)(Qt + r * 128 + sl * 16);
    }
  }
#pragma unroll
  for (int n = 0; n < 4; n++) {
    int r = n * 16 + l15;
#pragma unroll
    for (int kh = 0; kh < 2; kh++) {
      int sl = ((kh << 2) + l4) ^ (r & 7);
      bf16x8 kf = *(const bf16x8*)(Kt + r * 128 + sl * 16);
      acc[n] = MFMA16(qf[kh], kf, acc[n]);
    }
  }
  const int t0 = w * 16 + l4 * 4;
#pragma unroll
  for (int j = 0; j < 4; j++) {
    int t_ = t0 + j;
    float lv[4];
#pragma unroll
    for (int n = 0; n < 4; n++) {
      int s_ = n * 16 + l15;
      float x = acc[n][j];
      x += bf2f(*(const u16*)(B1 + t_ * 128 + ((s_ * 2) ^ ((t_ & 7) << 4))));
      x += bf2f(*(const u16*)(B2 + s_ * 128 + ((t_ * 2) ^ ((s_ & 7) << 4))));
      lv[n] = x * 0.125f;
    }
    float mx = fmaxf(fmaxf(lv[0], lv[1]), fmaxf(lv[2], lv[3]));
#pragma unroll
    for (int d = 1; d < 16; d <<= 1) mx = fmaxf(mx, __shfl_xor(mx, d, 64));
    float e0 = __expf(lv[0] - mx), e1 = __expf(lv[1] - mx);
    float e2 = __expf(lv[2] - mx), e3 = __expf(lv[3] - mx);
    float sum = e0 + e1 + e2 + e3;
#pragma unroll
    for (int d = 1; d < 16; d <<= 1) sum += __shfl_xor(sum, d, 64);
    float inv = 1.0f / sum;
    float pe[4] = {e0 * inv, e1 * inv, e2 * inv, e3 * inv};
#pragma unroll
    for (int n = 0; n < 4; n++) {
      int s_ = n * 16 + l15;
      *(u16*)(Pt + t_ * 128 + ((s_ * 2) ^ ((t_ & 7) << 4))) = f2bf(pe[n]);
    }
  }
  __syncthreads();
  // P -> global (linearized, undo swizzle)
#pragma unroll
  for (int c = 0; c < 2; c++) {
    int ch = c * 256 + tid;
    int r = ch >> 3, sl = ch & 7;
    uint4 v = *(const uint4*)(Pt + r * 128 + ((sl ^ (r & 7)) << 4));
    *((uint4*)(Pg + base) + ch) = v;
  }
  // out_v = P * V; V is [s][d] -> B-frags via scalar column gather
  f32x4 acc2[4] = {};
  bf16x8 pf[2];
  {
    int r = w * 16 + l15;
#pragma unroll
    for (int kh = 0; kh < 2; kh++) {
      int sl = ((kh << 2) + l4) ^ (r & 7);
      pf[kh] = *(const bf16x8*)(Pt + r * 128 + sl * 16);
    }
  }
#pragma unroll
  for (int n = 0; n < 4; n++) {
#pragma unroll
    for (int kh = 0; kh < 2; kh++) {
      bf16x8 tmp;
#pragma unroll
      for (int j = 0; j < 8; j++) {
        int s_ = (kh << 5) + (l4 << 3) + j;
        int d_ = n * 16 + l15;
        u16 uu = *(const u16*)(Vt + s_ * 128 + ((d_ * 2) ^ ((s_ & 7) << 4)));
        tmp[j] = __builtin_bit_cast(__bf16, uu);
      }
      acc2[n] = MFMA16(pf[kh], tmp, acc2[n]);
    }
  }
#pragma unroll
  for (int n = 0; n < 4; n++)
#pragma unroll
    for (int j = 0; j < 4; j++) {
      int t_ = t0 + j, d_ = n * 16 + l15;
      aout[((size_t)(b * 64 + t_)) * 1024 + h * 64 + d_] = f2bf(acc2[n][j]);
    }
}

// ---------------- out_relv: aout[b,t,h,d] += sum_s P[b,s]*rel_v[h,idx[t,s],d]
__global__ __launch_bounds__(256) void k_relv(
    const u16* __restrict__ Pg, const u16* __restrict__ relv,
    const int* __restrict__ relidx, u16* __restrict__ aout) {
  const int tid = threadIdx.x, lane = tid & 63, w = tid >> 6;
  const int l15 = lane & 15, l4 = lane >> 4;
  const int t = blockIdx.x, h = blockIdx.y, bc = blockIdx.z;
  __shared__ char lds[8192];
#pragma unroll
  for (int c = 0; c < 2; c++) {
    int ch = c * 256 + tid;
    int sr = ch >> 3, sl = (ch & 7) ^ (sr & 7);
    int ri = relidx[t * 64 + sr];
    g2l16(relv + ((size_t)h * 225 + ri) * 64 + sl * 8,
          lds + c * 4096 + w * 1024);
  }
  __syncthreads();
  bf16x8 bfr[4][2];
#pragma unroll
  for (int n = 0; n < 4; n++)
#pragma unroll
    for (int kh = 0; kh < 2; kh++) {
      bf16x8 tmp;
#pragma unroll
      for (int j = 0; j < 8; j++) {
        int s_ = (kh << 5) + (l4 << 3) + j;
        int d_ = n * 16 + l15;
        u16 u = *(const u16*)(lds + s_ * 128 + ((d_ * 2) ^ ((s_ & 7) << 4)));
        tmp[j] = __builtin_bit_cast(__bf16, u);
      }
      bfr[n][kh] = tmp;
    }
  f32x4 acc[4][4] = {};
#pragma unroll
  for (int m = 0; m < 4; m++) {
    int bb = bc * 256 + w * 64 + m * 16 + l15;
    const u16* ap = Pg + ((size_t)(bb * 16 + h)) * 4096 + t * 64 + l4 * 8;
    bf16x8 a0 = *(const bf16x8*)ap;
    bf16x8 a1 = *(const bf16x8*)(ap + 32);
#pragma unroll
    for (int n = 0; n < 4; n++) {
      acc[m][n] = MFMA16(a0, bfr[n][0], acc[m][n]);
      acc[m][n] = MFMA16(a1, bfr[n][1], acc[m][n]);
    }
  }
#pragma unroll
  for (int m = 0; m < 4; m++)
#pragma unroll
    for (int n = 0; n < 4; n++)
#pragma unroll
      for (int j = 0; j < 4; j++) {
        int bb = bc * 256 + w * 64 + m * 16 + l4 * 4 + j;
        int d_ = n * 16 + l15;
        size_t o = ((size_t)(bb * 64 + t)) * 1024 + h * 64 + d_;
        aout[o] = f2bf(bf2f(aout[o]) + acc[m][n][j]);
      }
}

extern "C" void kernel_launch(void* const* d_in, const int* in_sizes, int n_in,
                              void* d_out, int out_size, void* d_ws,
                              size_t ws_size, hipStream_t stream) {
  const float* x = (const float*)d_in[0];
  const float* Wq = (const float*)d_in[1];
  const float* bq = (const float*)d_in[2];
  const float* Wk = (const float*)d_in[3];
  const float* bk = (const float*)d_in[4];
  const float* Wv = (const float*)d_in[5];
  const float* bv = (const float*)d_in[6];
  const float* Wo = (const float*)d_in[7];
  const float* bo = (const float*)d_in[8];
  const float* rq = (const float*)d_in[9];
  const float* rk = (const float*)d_in[10];
  const float* rv = (const float*)d_in[11];
  const int* ridx = (const int*)d_in[12];
  float* out = (float*)d_out;

  char* ws = (char*)d_ws;
  const size_t MB = 1ull << 20;
  u16* xb = (u16*)(ws + 0);  // reused as P after k_gemm_qkv consumes it
  u16* Qb = (u16*)(ws + 64 * MB);
  u16* Kb = (u16*)(ws + 128 * MB);
  u16* Vb = (u16*)(ws + 192 * MB);
  u16* b1 = (u16*)(ws + 256 * MB);
  u16* b2 = (u16*)(ws + 320 * MB);
  u16* aout = (u16*)(ws + 384 * MB);
  u16* wqkv = (u16*)(ws + 448 * MB);
  u16* wo = (u16*)(ws + 454 * MB);
  u16* relq = (u16*)(ws + 456 * MB);
  u16* relk = (u16*)(ws + 457 * MB);
  u16* relv = (u16*)(ws + 458 * MB);
  u16* Pg = xb;

  k_cvt<<<32768, 256, 0, stream>>>(x, xb, 8388608);
  k_cvt<<<1024, 256, 0, stream>>>(Wq, wqkv, 262144);
  k_cvt<<<1024, 256, 0, stream>>>(Wk, wqkv + 1048576, 262144);
  k_cvt<<<1024, 256, 0, stream>>>(Wv, wqkv + 2097152, 262144);
  k_cvt<<<1024, 256, 0, stream>>>(Wo, wo, 262144);
  k_cvt<<<225, 256, 0, stream>>>(rq, relq, 57600);
  k_cvt<<<225, 256, 0, stream>>>(rk, relk, 57600);
  k_cvt<<<225, 256, 0, stream>>>(rv, relv, 57600);

  k_gemm_qkv<<<1536, 512, 0, stream>>>(xb, wqkv, bq, bk, bv, Qb, Kb, Vb);
  k_bias1<<<dim3(64, 16, 2), 256, 0, stream>>>(Qb, relq, relk, ridx, b1);
  k_bias2<<<dim3(64, 16, 2), 256, 0, stream>>>(Kb, relq, ridx, b2);
  k_attn<<<dim3(512, 16), 256, 0, stream>>>(Qb, Kb, Vb, b1, b2, Pg, aout);
  k_relv<<<dim3(64, 16, 2), 256, 0, stream>>>(Pg, relv, ridx, aout);
  k_gemm_out<<<512, 512, 0, stream>>>(aout, wo, bo, out);
}

// Round 6
// 548.279 us; speedup vs baseline: 1.1412x; 1.1412x over previous
//
#include <hip/hip_runtime.h>
#include <cstdint>

// ChessRelativeTransformer on MI355X (gfx950), bf16 MFMA pipeline.
// B=512 T=64 H=16 DH=64 D=1024 NUM_REL=225 scale=0.125
// R6: (1) ds_read addressing via 4 precomputed per-lane bases + imm offsets
//     (sub&7 == l15&7 identity -> segment/m/n fold into offset: immediates);
//     (2) coalesced LDS-bounce epilogues for both big GEMMs (acc->LDS f32,
//     read back row-major, 16B stores; was 128 scattered 2B stores/lane);
//     (3) schedule/waits unchanged from R5 (correct ledger).

typedef unsigned short u16;
typedef unsigned int u32;
typedef __bf16 bf16x8 __attribute__((ext_vector_type(8)));
typedef float f32x4 __attribute__((ext_vector_type(4)));

#define MFMA16(a, b, c) __builtin_amdgcn_mfma_f32_16x16x32_bf16(a, b, c, 0, 0, 0)

__device__ __forceinline__ u16 f2bf(float f) {
  u32 u = __builtin_bit_cast(u32, f);
  u = (u + 0x7FFFu + ((u >> 16) & 1u)) >> 16;
  return (u16)u;
}
__device__ __forceinline__ float bf2f(u16 h) {
  return __builtin_bit_cast(float, ((u32)h) << 16);
}

__device__ __forceinline__ void g2l16(const void* g, void* lds_wave_base) {
#if __has_builtin(__builtin_amdgcn_global_load_lds)
  __builtin_amdgcn_global_load_lds(
      (const __attribute__((address_space(1))) u32*)(uintptr_t)g,
      (__attribute__((address_space(3))) u32*)(uintptr_t)lds_wave_base, 16, 0, 0);
#else
  uint4 v = *(const uint4*)g;
  *(uint4*)((char*)lds_wave_base + (threadIdx.x & 63) * 16) = v;
#endif
}

// ---------------- fp32 -> bf16 convert (4 elems/thread) ----------------
__global__ __launch_bounds__(256) void k_cvt(const float* __restrict__ src,
                                             u16* __restrict__ dst, int nq) {
  int i = blockIdx.x * 256 + threadIdx.x;
  if (i >= nq) return;
  float4 v = ((const float4*)src)[i];
  ushort4 o;
  o.x = f2bf(v.x); o.y = f2bf(v.y); o.z = f2bf(v.z); o.w = f2bf(v.w);
  ((ushort4*)dst)[i] = o;
}

// ================= 256x256 8-phase GEMM core (R5 schedule, R6 addressing) ==
// C = A * Bm^T. 512 thr = 8 waves (2M x 4N), BK=64, 128KiB dbuf LDS.
// LDS fragment read address = lane-base[kk] + imm(segment + m*2048), since
// sub&7 == l15&7 (m*16, n*16, wr*64, wc*32 all ==0 mod 8).

__device__ __forceinline__ void stageA(const u16* __restrict__ A, int row0,
                                       int kb, char* lds, int buf, int half,
                                       int tid) {
#pragma unroll
  for (int g = 0; g < 2; g++) {
    int ch = g * 512 + tid;
    int sub = ch >> 3, sl = ch & 7;
    int R = (sub & 63) | (half << 6) | ((sub & 64) << 1);
    int kg = sl ^ (sub & 7);
    g2l16(A + (size_t)(row0 + R) * 1024 + kb + kg * 8,
          lds + (buf * 2 + half) * 16384 + g * 8192 + (tid >> 6) * 1024);
  }
}
__device__ __forceinline__ void stageB(const u16* __restrict__ Bm, int col0,
                                       int kb, char* lds, int buf, int half,
                                       int tid) {
#pragma unroll
  for (int g = 0; g < 2; g++) {
    int ch = g * 512 + tid;
    int sub = ch >> 3, sl = ch & 7;
    int C = (sub & 31) | (half << 5) | ((sub & 0x60) << 1);
    int kg = sl ^ (sub & 7);
    g2l16(Bm + (size_t)(col0 + C) * 1024 + kb + kg * 8,
          lds + 65536 + (buf * 2 + half) * 16384 + g * 8192 + (tid >> 6) * 1024);
  }
}

// CBUF: compile-time current buffer. RA: 0 none, 1 -> afA, 2 -> afC.
// RB: 0 none, 1 -> bfB. USEA: 0 afA, 1 afC. SMAT: 0 stage A, 1 stage B.
template <int CBUF, int MH, int NH, int RA, int RB, int USEA, int SMAT,
          int SHALF, int SBUF, int KADD, int VMn>
__device__ __forceinline__ void phz(const u16* __restrict__ A,
                                    const u16* __restrict__ Bm, int row0,
                                    int col0, int k0, char* lds,
                                    f32x4 (&acc)[8][4], bf16x8 (&afA)[4][2],
                                    bf16x8 (&afC)[4][2], bf16x8 (&bfB)[2][2],
                                    const int* abase, const int* bbase,
                                    int tid, bool st) {
  if (RA) {
#pragma unroll
    for (int m = 0; m < 4; m++)
#pragma unroll
      for (int kk = 0; kk < 2; kk++) {
        bf16x8 v = *(const bf16x8*)(lds + abase[kk] +
                                    ((CBUF * 2 + MH) * 16384 + m * 2048));
        if (RA == 1) afA[m][kk] = v; else afC[m][kk] = v;
      }
  }
  if (RB) {
#pragma unroll
    for (int n = 0; n < 2; n++)
#pragma unroll
      for (int kk = 0; kk < 2; kk++)
        bfB[n][kk] = *(const bf16x8*)(lds + bbase[kk] +
                                      ((CBUF * 2 + NH) * 16384 + n * 2048));
  }
  if (st) {
    if (SMAT == 0)
      stageA(A, row0, k0 + KADD * 64, lds, SBUF, SHALF, tid);
    else
      stageB(Bm, col0, k0 + KADD * 64, lds, SBUF, SHALF, tid);
  }
  __builtin_amdgcn_s_barrier();
  asm volatile("s_waitcnt lgkmcnt(0)" ::: "memory");
  __builtin_amdgcn_sched_barrier(0);
  __builtin_amdgcn_s_setprio(1);
#pragma unroll
  for (int m = 0; m < 4; m++)
#pragma unroll
    for (int n = 0; n < 2; n++)
#pragma unroll
      for (int kk = 0; kk < 2; kk++)
        acc[MH * 4 + m][NH * 2 + n] = MFMA16(USEA ? afC[m][kk] : afA[m][kk],
                                             bfB[n][kk],
                                             acc[MH * 4 + m][NH * 2 + n]);
  __builtin_amdgcn_s_setprio(0);
  if constexpr (VMn == 8) asm volatile("s_waitcnt vmcnt(8)" ::: "memory");
  else if constexpr (VMn == 6) asm volatile("s_waitcnt vmcnt(6)" ::: "memory");
  else if constexpr (VMn == 4) asm volatile("s_waitcnt vmcnt(4)" ::: "memory");
  else if constexpr (VMn == 2) asm volatile("s_waitcnt vmcnt(2)" ::: "memory");
  else if constexpr (VMn == 0) asm volatile("s_waitcnt vmcnt(0)" ::: "memory");
  __builtin_amdgcn_s_barrier();
}

__device__ __forceinline__ void gemm256_core(const u16* __restrict__ A,
                                             const u16* __restrict__ Bm,
                                             int row0, int col0, char* lds,
                                             f32x4 (&acc)[8][4], int tid) {
  const int lane = tid & 63, w = tid >> 6;
  const int wr = w >> 2, wc = w & 3;
  const int l15 = lane & 15, l4 = lane >> 4;
  const int l7 = l15 & 7;
  int abase[2], bbase[2];
#pragma unroll
  for (int kk = 0; kk < 2; kk++) {
    int swz = ((kk * 4 + l4) ^ l7) << 4;
    abase[kk] = wr * 8192 + l15 * 128 + swz;
    bbase[kk] = 65536 + wc * 4096 + l15 * 128 + swz;
  }
  bf16x8 afA[4][2], afC[4][2], bfB[2][2];
  // prologue: tile0 all 4 halves (buf0) + tile1 B0,A1 (buf1); drain tile0.
  stageA(A, row0, 0, lds, 0, 0, tid);
  stageB(Bm, col0, 0, lds, 0, 0, tid);
  stageA(A, row0, 0, lds, 0, 1, tid);
  stageB(Bm, col0, 0, lds, 0, 1, tid);
  stageB(Bm, col0, 64, lds, 1, 0, tid);
  stageA(A, row0, 64, lds, 1, 1, tid);
  asm volatile("s_waitcnt vmcnt(4)" ::: "memory");
  __builtin_amdgcn_s_barrier();
  for (int u = 0; u < 7; ++u) {
    int k0 = u * 128;
    phz<0,0,0,1,1,0, 0,0,1,1,-1>(A,Bm,row0,col0,k0,lds,acc,afA,afC,bfB,abase,bbase,tid,true);
    phz<0,1,0,2,0,1, 1,1,1,1, 8>(A,Bm,row0,col0,k0,lds,acc,afA,afC,bfB,abase,bbase,tid,true);
    phz<0,1,1,0,1,1, 1,0,0,2,-1>(A,Bm,row0,col0,k0,lds,acc,afA,afC,bfB,abase,bbase,tid,true);
    phz<0,0,1,0,0,0, 0,1,0,2, 6>(A,Bm,row0,col0,k0,lds,acc,afA,afC,bfB,abase,bbase,tid,true);
    phz<1,0,0,1,1,0, 0,0,0,2,-1>(A,Bm,row0,col0,k0,lds,acc,afA,afC,bfB,abase,bbase,tid,true);
    phz<1,1,0,2,0,1, 1,1,0,2, 8>(A,Bm,row0,col0,k0,lds,acc,afA,afC,bfB,abase,bbase,tid,true);
    phz<1,1,1,0,1,1, 1,0,1,3,-1>(A,Bm,row0,col0,k0,lds,acc,afA,afC,bfB,abase,bbase,tid,true);
    phz<1,0,1,0,0,0, 0,1,1,3, 6>(A,Bm,row0,col0,k0,lds,acc,afA,afC,bfB,abase,bbase,tid,true);
  }
  {  // peeled final iteration (tiles 14,15): stage A0[15]@P1, B1[15]@P2;
     // drains: P2 vm(8), P4 vm(2), P6 vm(0).
    const int k0 = 896;
    phz<0,0,0,1,1,0, 0,0,1,1,-1>(A,Bm,row0,col0,k0,lds,acc,afA,afC,bfB,abase,bbase,tid,true);
    phz<0,1,0,2,0,1, 1,1,1,1, 8>(A,Bm,row0,col0,k0,lds,acc,afA,afC,bfB,abase,bbase,tid,true);
    phz<0,1,1,0,1,1, 0,0,0,0,-1>(A,Bm,row0,col0,k0,lds,acc,afA,afC,bfB,abase,bbase,tid,false);
    phz<0,0,1,0,0,0, 0,0,0,0, 2>(A,Bm,row0,col0,k0,lds,acc,afA,afC,bfB,abase,bbase,tid,false);
    phz<1,0,0,1,1,0, 0,0,0,0,-1>(A,Bm,row0,col0,k0,lds,acc,afA,afC,bfB,abase,bbase,tid,false);
    phz<1,1,0,2,0,1, 0,0,0,0, 0>(A,Bm,row0,col0,k0,lds,acc,afA,afC,bfB,abase,bbase,tid,false);
    phz<1,1,1,0,1,1, 0,0,0,0,-1>(A,Bm,row0,col0,k0,lds,acc,afA,afC,bfB,abase,bbase,tid,false);
    phz<1,0,1,0,0,0, 0,0,0,0,-1>(A,Bm,row0,col0,k0,lds,acc,afA,afC,bfB,abase,bbase,tid,false);
  }
}

// ---------------- QKV GEMM: [32768x1024] x [3072x1024]^T ----------------
__global__ __launch_bounds__(512, 2) void k_gemm_qkv(
    const u16* __restrict__ A, const u16* __restrict__ Bm,
    const float* __restrict__ bq, const float* __restrict__ bk,
    const float* __restrict__ bv, u16* __restrict__ Qb, u16* __restrict__ Kb,
    u16* __restrict__ Vb) {
  __shared__ char lds[131072];
  const int tid = threadIdx.x;
  const int lane = tid & 63, w = tid >> 6;
  const int wr = w >> 2, wc = w & 3;
  const int l15 = lane & 15, l4 = lane >> 4;
  int f = blockIdx.x;
  int swz = (f & 7) * 192 + (f >> 3);
  int bcol = swz % 12, brow = swz / 12;
  const int row0 = brow * 256, col0 = bcol * 256;
  f32x4 acc[8][4] = {};
  gemm256_core(A, Bm, row0, col0, lds, acc, tid);
  // ---- coalesced epilogue via LDS bounce (wave-private 16KB region) ----
  char* eb = lds + w * 16384;
  const int colW = col0 + wc * 64;
  const int sel = colW >> 10, hd = colW & 1023;
  const int h = hd >> 6;
  const float* bp = (sel == 0) ? bq : (sel == 1) ? bk : bv;
  const float* biasW = bp + hd;
  u16* dstW = (sel == 0) ? Qb : (sel == 1) ? Kb : Vb;
#pragma unroll
  for (int r = 0; r < 4; r++) {
#pragma unroll
    for (int mm = 0; mm < 2; mm++) {
      int mf = r * 2 + mm;
#pragma unroll
      for (int nf = 0; nf < 4; nf++)
#pragma unroll
        for (int j = 0; j < 4; j++) {
          int rowl = mm * 16 + l4 * 4 + j;
          *(float*)(eb + rowl * 272 + (nf * 16 + l15) * 4) = acc[mf][nf][j];
        }
    }
    asm volatile("s_waitcnt lgkmcnt(0)" ::: "memory");
    __builtin_amdgcn_sched_barrier(0);
#pragma unroll
    for (int it = 0; it < 4; it++) {
      int u = it * 64 + lane;
      int rowl = u >> 3, ch = u & 7;
      float4 a0 = *(const float4*)(eb + rowl * 272 + ch * 32);
      float4 a1 = *(const float4*)(eb + rowl * 272 + ch * 32 + 16);
      float4 b0 = *(const float4*)(biasW + ch * 8);
      float4 b1 = *(const float4*)(biasW + ch * 8 + 4);
      uint4 pk;
      pk.x = (u32)f2bf(a0.x + b0.x) | ((u32)f2bf(a0.y + b0.y) << 16);
      pk.y = (u32)f2bf(a0.z + b0.z) | ((u32)f2bf(a0.w + b0.w) << 16);
      pk.z = (u32)f2bf(a1.x + b1.x) | ((u32)f2bf(a1.y + b1.y) << 16);
      pk.w = (u32)f2bf(a1.z + b1.z) | ((u32)f2bf(a1.w + b1.w) << 16);
      int row = row0 + wr * 128 + r * 32 + rowl;
      int b = row >> 6, t = row & 63;
      *(uint4*)(dstW + ((size_t)(b * 16 + h)) * 4096 + t * 64 + ch * 8) = pk;
    }
    asm volatile("s_waitcnt lgkmcnt(0)" ::: "memory");
    __builtin_amdgcn_sched_barrier(0);
  }
}

// ---------------- output GEMM: [32768x1024] x [1024x1024]^T + bias -> fp32 --
__global__ __launch_bounds__(512, 2) void k_gemm_out(
    const u16* __restrict__ A, const u16* __restrict__ Bm,
    const float* __restrict__ bo, float* __restrict__ out) {
  __shared__ char lds[131072];
  const int tid = threadIdx.x;
  const int lane = tid & 63, w = tid >> 6;
  const int wr = w >> 2, wc = w & 3;
  const int l15 = lane & 15, l4 = lane >> 4;
  int f = blockIdx.x;  // 512 blocks = 8 chunks of 64, col-fastest
  int swz = (f & 7) * 64 + (f >> 3);
  int bcol = swz & 3, brow = swz >> 2;
  const int row0 = brow * 256, col0 = bcol * 256;
  f32x4 acc[8][4] = {};
  gemm256_core(A, Bm, row0, col0, lds, acc, tid);
  // ---- coalesced epilogue via LDS bounce ----
  char* eb = lds + w * 16384;
  const int colW = col0 + wc * 64;
  const float* biasW = bo + colW;
#pragma unroll
  for (int r = 0; r < 4; r++) {
#pragma unroll
    for (int mm = 0; mm < 2; mm++) {
      int mf = r * 2 + mm;
#pragma unroll
      for (int nf = 0; nf < 4; nf++)
#pragma unroll
        for (int j = 0; j < 4; j++) {
          int rowl = mm * 16 + l4 * 4 + j;
          *(float*)(eb + rowl * 272 + (nf * 16 + l15) * 4) = acc[mf][nf][j];
        }
    }
    asm volatile("s_waitcnt lgkmcnt(0)" ::: "memory");
    __builtin_amdgcn_sched_barrier(0);
#pragma unroll
    for (int it = 0; it < 8; it++) {
      int u = it * 64 + lane;
      int rowl = u >> 4, ch = u & 15;
      float4 a0 = *(const float4*)(eb + rowl * 272 + ch * 16);
      float4 b0 = *(const float4*)(biasW + ch * 4);
      a0.x += b0.x; a0.y += b0.y; a0.z += b0.z; a0.w += b0.w;
      int row = row0 + wr * 128 + r * 32 + rowl;
      *(float4*)(out + (size_t)row * 1024 + colW + ch * 4) = a0;
    }
    asm volatile("s_waitcnt lgkmcnt(0)" ::: "memory");
    __builtin_amdgcn_sched_barrier(0);
  }
}

// ---------------- bias1[b,h,t,s] = sum_d q[b,h,t,d]*rel_k[h,idx[t,s],d] + T3
__global__ __launch_bounds__(256) void k_bias1(
    const u16* __restrict__ Qb, const u16* __restrict__ relq,
    const u16* __restrict__ relk, const int* __restrict__ relidx,
    u16* __restrict__ bias1) {
  const int tid = threadIdx.x, lane = tid & 63, w = tid >> 6;
  const int l15 = lane & 15, l4 = lane >> 4;
  const int t = blockIdx.x, h = blockIdx.y, bc = blockIdx.z;
  __shared__ char lds[16640];
  char* RK = lds;
  char* RQ = lds + 8192;
  float* T3 = (float*)(lds + 16384);
#pragma unroll
  for (int c = 0; c < 2; c++) {
    int ch = c * 256 + tid;
    int sr = ch >> 3, sl = (ch & 7) ^ (sr & 7);
    int ri = relidx[t * 64 + sr];
    size_t so = ((size_t)h * 225 + ri) * 64 + sl * 8;
    g2l16(relk + so, RK + c * 4096 + w * 1024);
    g2l16(relq + so, RQ + c * 4096 + w * 1024);
  }
  __syncthreads();
  if (tid < 64) {
    int sr = tid;
    float sum = 0.f;
#pragma unroll
    for (int sl = 0; sl < 8; sl++) {
      int o = sr * 128 + ((sl ^ (sr & 7)) << 4);
      bf16x8 aq = *(const bf16x8*)(RQ + o);
      bf16x8 ak = *(const bf16x8*)(RK + o);
#pragma unroll
      for (int j = 0; j < 8; j++) sum += (float)aq[j] * (float)ak[j];
    }
    T3[sr] = sum;
  }
  bf16x8 bfr[4][2];
#pragma unroll
  for (int n = 0; n < 4; n++)
#pragma unroll
    for (int kh = 0; kh < 2; kh++) {
      int r = n * 16 + l15;
      int sl = ((kh << 2) + l4) ^ (r & 7);
      bfr[n][kh] = *(const bf16x8*)(RK + r * 128 + sl * 16);
    }
  __syncthreads();
  f32x4 acc[4][4] = {};
#pragma unroll
  for (int m = 0; m < 4; m++) {
    int bb = bc * 256 + w * 64 + m * 16 + l15;
    const u16* ap = Qb + ((size_t)(bb * 16 + h)) * 4096 + t * 64 + l4 * 8;
    bf16x8 a0 = *(const bf16x8*)ap;
    bf16x8 a1 = *(const bf16x8*)(ap + 32);
#pragma unroll
    for (int n = 0; n < 4; n++) {
      acc[m][n] = MFMA16(a0, bfr[n][0], acc[m][n]);
      acc[m][n] = MFMA16(a1, bfr[n][1], acc[m][n]);
    }
  }
#pragma unroll
  for (int m = 0; m < 4; m++)
#pragma unroll
    for (int n = 0; n < 4; n++)
#pragma unroll
      for (int j = 0; j < 4; j++) {
        int bb = bc * 256 + w * 64 + m * 16 + l4 * 4 + j;
        int s_ = n * 16 + l15;
        bias1[((size_t)(bb * 16 + h)) * 4096 + t * 64 + s_] =
            f2bf(acc[m][n][j] + T3[s_]);
      }
}

// ---------------- bias2[b,h,s,t] = sum_d rel_q[h,idx[t,s],d]*k[b,h,s,d]
__global__ __launch_bounds__(256) void k_bias2(
    const u16* __restrict__ Kb, const u16* __restrict__ relq,
    const int* __restrict__ relidx, u16* __restrict__ bias2) {
  const int tid = threadIdx.x, lane = tid & 63, w = tid >> 6;
  const int l15 = lane & 15, l4 = lane >> 4;
  const int s = blockIdx.x, h = blockIdx.y, bc = blockIdx.z;
  __shared__ char lds[8192];
#pragma unroll
  for (int c = 0; c < 2; c++) {
    int ch = c * 256 + tid;
    int tq = ch >> 3, sl = (ch & 7) ^ (tq & 7);
    int ri = relidx[tq * 64 + s];
    g2l16(relq + ((size_t)h * 225 + ri) * 64 + sl * 8,
          lds + c * 4096 + w * 1024);
  }
  __syncthreads();
  bf16x8 bfr[4][2];
#pragma unroll
  for (int n = 0; n < 4; n++)
#pragma unroll
    for (int kh = 0; kh < 2; kh++) {
      int r = n * 16 + l15;
      int sl = ((kh << 2) + l4) ^ (r & 7);
      bfr[n][kh] = *(const bf16x8*)(lds + r * 128 + sl * 16);
    }
  f32x4 acc[4][4] = {};
#pragma unroll
  for (int m = 0; m < 4; m++) {
    int bb = bc * 256 + w * 64 + m * 16 + l15;
    const u16* ap = Kb + ((size_t)(bb * 16 + h)) * 4096 + s * 64 + l4 * 8;
    bf16x8 a0 = *(const bf16x8*)ap;
    bf16x8 a1 = *(const bf16x8*)(ap + 32);
#pragma unroll
    for (int n = 0; n < 4; n++) {
      acc[m][n] = MFMA16(a0, bfr[n][0], acc[m][n]);
      acc[m][n] = MFMA16(a1, bfr[n][1], acc[m][n]);
    }
  }
#pragma unroll
  for (int m = 0; m < 4; m++)
#pragma unroll
    for (int n = 0; n < 4; n++)
#pragma unroll
      for (int j = 0; j < 4; j++) {
        int bb = bc * 256 + w * 64 + m * 16 + l4 * 4 + j;
        int tcol = n * 16 + l15;
        bias2[((size_t)(bb * 16 + h)) * 4096 + s * 64 + tcol] =
            f2bf(acc[m][n][j]);
      }
}

// ---------------- attention per (b,h): S=QK^T + b1 + b2^T, softmax, P, PV ----
__global__ __launch_bounds__(256) void k_attn(
    const u16* __restrict__ Qb, const u16* __restrict__ Kb,
    const u16* __restrict__ Vb, const u16* __restrict__ b1g,
    const u16* __restrict__ b2g, u16* __restrict__ Pg,
    u16* __restrict__ aout) {
  const int tid = threadIdx.x, lane = tid & 63, w = tid >> 6;
  const int l15 = lane & 15, l4 = lane >> 4;
  const int b = blockIdx.x, h = blockIdx.y;
  __shared__ char lds[49152];
  char* Qt = lds;
  char* Kt = lds + 8192;
  char* Vt = lds + 16384;  // natural [s][d] layout
  char* B1 = lds + 24576;
  char* B2 = lds + 32768;
  char* Pt = lds + 40960;
  const size_t base = ((size_t)(b * 16 + h)) * 4096;
#pragma unroll
  for (int c = 0; c < 2; c++) {
    int ch = c * 256 + tid;
    int r = ch >> 3, sl = (ch & 7) ^ (r & 7);
    size_t so = base + r * 64 + sl * 8;
    int dst = c * 4096 + w * 1024;
    g2l16(Qb + so, Qt + dst);
    g2l16(Kb + so, Kt + dst);
    g2l16(Vb + so, Vt + dst);
    g2l16(b1g + so, B1 + dst);
    g2l16(b2g + so, B2 + dst);
  }
  __syncthreads();
  // S = Q K^T, wave w owns rows [w*16, w*16+16)
  f32x4 acc[4] = {};
  bf16x8 qf[2];
  {
    int r = w * 16 + l15;
#pragma unroll
    for (int kh = 0; kh < 2; kh++) {
      int sl = ((kh << 2) + l4) ^ (r & 7);
      qf[kh] = *(const bf16x8*)(Qt + r * 128 + sl * 16);
    }
  }
#pragma unroll
  for (int n = 0; n < 4; n++) {
    int r = n * 16 + l15;
#pragma unroll
    for (int kh = 0; kh < 2; kh++) {
      int sl = ((kh << 2) + l4) ^ (r & 7);
      bf16x8 kf = *(const bf16x8*)(Kt + r * 128 + sl * 16);
      acc[n] = MFMA16(qf[kh], kf, acc[n]);
    }
  }
  const int t0 = w * 16 + l4 * 4;
#pragma unroll
  for (int j = 0; j < 4; j++) {
    int t_ = t0 + j;
    float lv[4];
#pragma unroll
    for (int n = 0; n < 4; n++) {
      int s_ = n * 16 + l15;
      float x = acc[n][j];
      x += bf2f(*(const u16*)(B1 + t_ * 128 + ((s_ * 2) ^ ((t_ & 7) << 4))));
      x += bf2f(*(const u16*)(B2 + s_ * 128 + ((t_ * 2) ^ ((s_ & 7) << 4))));
      lv[n] = x * 0.125f;
    }
    float mx = fmaxf(fmaxf(lv[0], lv[1]), fmaxf(lv[2], lv[3]));
#pragma unroll
    for (int d = 1; d < 16; d <<= 1) mx = fmaxf(mx, __shfl_xor(mx, d, 64));
    float e0 = __expf(lv[0] - mx), e1 = __expf(lv[1] - mx);
    float e2 = __expf(lv[2] - mx), e3 = __expf(lv[3] - mx);
    float sum = e0 + e1 + e2 + e3;
#pragma unroll
    for (int d = 1; d < 16; d <<= 1) sum += __shfl_xor(sum, d, 64);
    float inv = 1.0f / sum;
    float pe[4] = {e0 * inv, e1 * inv, e2 * inv, e3 * inv};
#pragma unroll
    for (int n = 0; n < 4; n++) {
      int s_ = n * 16 + l15;
      *(u16*)(Pt + t_ * 128 + ((s_ * 2) ^ ((t_ & 7) << 4))) = f2bf(pe[n]);
    }
  }
  __syncthreads();
  // P -> global (linearized, undo swizzle)
#pragma unroll
  for (int c = 0; c < 2; c++) {
    int ch = c * 256 + tid;
    int r = ch >> 3, sl = ch & 7;
    uint4 v = *(const uint4*)(Pt + r * 128 + ((sl ^ (r & 7)) << 4));
    *((uint4*)(Pg + base) + ch) = v;
  }
  // out_v = P * V; V is [s][d] -> B-frags via scalar column gather
  f32x4 acc2[4] = {};
  bf16x8 pf[2];
  {
    int r = w * 16 + l15;
#pragma unroll
    for (int kh = 0; kh < 2; kh++) {
      int sl = ((kh << 2) + l4) ^ (r & 7);
      pf[kh] = *(const bf16x8*)(Pt + r * 128 + sl * 16);
    }
  }
#pragma unroll
  for (int n = 0; n < 4; n++) {
#pragma unroll
    for (int kh = 0; kh < 2; kh++) {
      bf16x8 tmp;
#pragma unroll
      for (int j = 0; j < 8; j++) {
        int s_ = (kh << 5) + (l4 << 3) + j;
        int d_ = n * 16 + l15;
        u16 uu = *(const u16*)(Vt + s_ * 128 + ((d_ * 2) ^ ((s_ & 7) << 4)));
        tmp[j] = __builtin_bit_cast(__bf16, uu);
      }
      acc2[n] = MFMA16(pf[kh], tmp, acc2[n]);
    }
  }
#pragma unroll
  for (int n = 0; n < 4; n++)
#pragma unroll
    for (int j = 0; j < 4; j++) {
      int t_ = t0 + j, d_ = n * 16 + l15;
      aout[((size_t)(b * 64 + t_)) * 1024 + h * 64 + d_] = f2bf(acc2[n][j]);
    }
}

// ---------------- out_relv: aout[b,t,h,d] += sum_s P[b,s]*rel_v[h,idx[t,s],d]
__global__ __launch_bounds__(256) void k_relv(
    const u16* __restrict__ Pg, const u16* __restrict__ relv,
    const int* __restrict__ relidx, u16* __restrict__ aout) {
  const int tid = threadIdx.x, lane = tid & 63, w = tid >> 6;
  const int l15 = lane & 15, l4 = lane >> 4;
  const int t = blockIdx.x, h = blockIdx.y, bc = blockIdx.z;
  __shared__ char lds[8192];
#pragma unroll
  for (int c = 0; c < 2; c++) {
    int ch = c * 256 + tid;
    int sr = ch >> 3, sl = (ch & 7) ^ (sr & 7);
    int ri = relidx[t * 64 + sr];
    g2l16(relv + ((size_t)h * 225 + ri) * 64 + sl * 8,
          lds + c * 4096 + w * 1024);
  }
  __syncthreads();
  bf16x8 bfr[4][2];
#pragma unroll
  for (int n = 0; n < 4; n++)
#pragma unroll
    for (int kh = 0; kh < 2; kh++) {
      bf16x8 tmp;
#pragma unroll
      for (int j = 0; j < 8; j++) {
        int s_ = (kh << 5) + (l4 << 3) + j;
        int d_ = n * 16 + l15;
        u16 u = *(const u16*)(lds + s_ * 128 + ((d_ * 2) ^ ((s_ & 7) << 4)));
        tmp[j] = __builtin_bit_cast(__bf16, u);
      }
      bfr[n][kh] = tmp;
    }
  f32x4 acc[4][4] = {};
#pragma unroll
  for (int m = 0; m < 4; m++) {
    int bb = bc * 256 + w * 64 + m * 16 + l15;
    const u16* ap = Pg + ((size_t)(bb * 16 + h)) * 4096 + t * 64 + l4 * 8;
    bf16x8 a0 = *(const bf16x8*)ap;
    bf16x8 a1 = *(const bf16x8*)(ap + 32);
#pragma unroll
    for (int n = 0; n < 4; n++) {
      acc[m][n] = MFMA16(a0, bfr[n][0], acc[m][n]);
      acc[m][n] = MFMA16(a1, bfr[n][1], acc[m][n]);
    }
  }
#pragma unroll
  for (int m = 0; m < 4; m++)
#pragma unroll
    for (int n = 0; n < 4; n++)
#pragma unroll
      for (int j = 0; j < 4; j++) {
        int bb = bc * 256 + w * 64 + m * 16 + l4 * 4 + j;
        int d_ = n * 16 + l15;
        size_t o = ((size_t)(bb * 64 + t)) * 1024 + h * 64 + d_;
        aout[o] = f2bf(bf2f(aout[o]) + acc[m][n][j]);
      }
}

extern "C" void kernel_launch(void* const* d_in, const int* in_sizes, int n_in,
                              void* d_out, int out_size, void* d_ws,
                              size_t ws_size, hipStream_t stream) {
  const float* x = (const float*)d_in[0];
  const float* Wq = (const float*)d_in[1];
  const float* bq = (const float*)d_in[2];
  const float* Wk = (const float*)d_in[3];
  const float* bk = (const float*)d_in[4];
  const float* Wv = (const float*)d_in[5];
  const float* bv = (const float*)d_in[6];
  const float* Wo = (const float*)d_in[7];
  const float* bo = (const float*)d_in[8];
  const float* rq = (const float*)d_in[9];
  const float* rk = (const float*)d_in[10];
  const float* rv = (const float*)d_in[11];
  const int* ridx = (const int*)d_in[12];
  float* out = (float*)d_out;

  char* ws = (char*)d_ws;
  const size_t MB = 1ull << 20;
  u16* xb = (u16*)(ws + 0);  // reused as P after k_gemm_qkv consumes it
  u16* Qb = (u16*)(ws + 64 * MB);
  u16* Kb = (u16*)(ws + 128 * MB);
  u16* Vb = (u16*)(ws + 192 * MB);
  u16* b1 = (u16*)(ws + 256 * MB);
  u16* b2 = (u16*)(ws + 320 * MB);
  u16* aout = (u16*)(ws + 384 * MB);
  u16* wqkv = (u16*)(ws + 448 * MB);
  u16* wo = (u16*)(ws + 454 * MB);
  u16* relq = (u16*)(ws + 456 * MB);
  u16* relk = (u16*)(ws + 457 * MB);
  u16* relv = (u16*)(ws + 458 * MB);
  u16* Pg = xb;

  k_cvt<<<32768, 256, 0, stream>>>(x, xb, 8388608);
  k_cvt<<<1024, 256, 0, stream>>>(Wq, wqkv, 262144);
  k_cvt<<<1024, 256, 0, stream>>>(Wk, wqkv + 1048576, 262144);
  k_cvt<<<1024, 256, 0, stream>>>(Wv, wqkv + 2097152, 262144);
  k_cvt<<<1024, 256, 0, stream>>>(Wo, wo, 262144);
  k_cvt<<<225, 256, 0, stream>>>(rq, relq, 57600);
  k_cvt<<<225, 256, 0, stream>>>(rk, relk, 57600);
  k_cvt<<<225, 256, 0, stream>>>(rv, relv, 57600);

  k_gemm_qkv<<<1536, 512, 0, stream>>>(xb, wqkv, bq, bk, bv, Qb, Kb, Vb);
  k_bias1<<<dim3(64, 16, 2), 256, 0, stream>>>(Qb, relq, relk, ridx, b1);
  k_bias2<<<dim3(64, 16, 2), 256, 0, stream>>>(Kb, relq, ridx, b2);
  k_attn<<<dim3(512, 16), 256, 0, stream>>>(Qb, Kb, Vb, b1, b2, Pg, aout);
  k_relv<<<dim3(64, 16, 2), 256, 0, stream>>>(Pg, relv, ridx, aout);
  k_gemm_out<<<512, 512, 0, stream>>>(aout, wo, bo, out);
}

// Round 7
// 534.949 us; speedup vs baseline: 1.1697x; 1.0249x over previous
//
#include <hip/hip_runtime.h>
#include <cstdint>

// ChessRelativeTransformer on MI355X (gfx950), bf16 MFMA pipeline.
// B=512 T=64 H=16 DH=64 D=1024 NUM_REL=225 scale=0.125
// R7: 6-phase/2-K-tile GEMM core (was 8): q01 folded into q11's phase
//     (32 MFMA there) -> 25% fewer barrier-pairs. Staging addresses hoisted
//     to per-lane base pointers + additive const offsets. Ledger:
//     stages P1:A0[o] P2:B1[o] P3:B0,A1[e+2] P4:A0[e+2] P5:B1[e+2]
//     P6:B0,A1[o+2]; waits P3:vm6 P5:vm8 P6:vm4; steady Q_in=4; epilogue
//     stages A0/B1[15] only, drains vm2 (P3) -> vm0 (P5).

typedef unsigned short u16;
typedef unsigned int u32;
typedef __bf16 bf16x8 __attribute__((ext_vector_type(8)));
typedef float f32x4 __attribute__((ext_vector_type(4)));

#define MFMA16(a, b, c) __builtin_amdgcn_mfma_f32_16x16x32_bf16(a, b, c, 0, 0, 0)

__device__ __forceinline__ u16 f2bf(float f) {
  u32 u = __builtin_bit_cast(u32, f);
  u = (u + 0x7FFFu + ((u >> 16) & 1u)) >> 16;
  return (u16)u;
}
__device__ __forceinline__ float bf2f(u16 h) {
  return __builtin_bit_cast(float, ((u32)h) << 16);
}

__device__ __forceinline__ void g2l16(const void* g, void* lds_wave_base) {
#if __has_builtin(__builtin_amdgcn_global_load_lds)
  __builtin_amdgcn_global_load_lds(
      (const __attribute__((address_space(1))) u32*)(uintptr_t)g,
      (__attribute__((address_space(3))) u32*)(uintptr_t)lds_wave_base, 16, 0, 0);
#else
  uint4 v = *(const uint4*)g;
  *(uint4*)((char*)lds_wave_base + (threadIdx.x & 63) * 16) = v;
#endif
}

// ---------------- fp32 -> bf16 convert (4 elems/thread) ----------------
__global__ __launch_bounds__(256) void k_cvt(const float* __restrict__ src,
                                             u16* __restrict__ dst, int nq) {
  int i = blockIdx.x * 256 + threadIdx.x;
  if (i >= nq) return;
  float4 v = ((const float4*)src)[i];
  ushort4 o;
  o.x = f2bf(v.x); o.y = f2bf(v.y); o.z = f2bf(v.z); o.w = f2bf(v.w);
  ((ushort4*)dst)[i] = o;
}

// ================= 256x256 6-phase GEMM core (R7) =================
// C = A * Bm^T. 512 thr = 8 waves (2M x 4N), BK=64, 128KiB dbuf LDS.
// LDS map (byte offsets): A half at (buf*2+half)*16384; B at 65536 + same.
// Tile e=2u -> buf0, o=2u+1 -> buf1 (static per phase).

template <int OFF>
__device__ __forceinline__ void rdAf(const char* lds, const int* abase,
                                     bf16x8 (&f)[4][2]) {
#pragma unroll
  for (int m = 0; m < 4; m++)
#pragma unroll
    for (int kk = 0; kk < 2; kk++)
      f[m][kk] = *(const bf16x8*)(lds + abase[kk] + OFF + m * 2048);
}
template <int OFF>
__device__ __forceinline__ void rdBf(const char* lds, const int* bbase,
                                     bf16x8 (&f)[2][2]) {
#pragma unroll
  for (int n = 0; n < 2; n++)
#pragma unroll
    for (int kk = 0; kk < 2; kk++)
      f[n][kk] = *(const bf16x8*)(lds + bbase[kk] + OFF + n * 2048);
}
__device__ __forceinline__ void mq(f32x4 (&acc)[8][4], const bf16x8 (&af)[4][2],
                                   const bf16x8 (&bf)[2][2], int MR, int NC) {
#pragma unroll
  for (int m = 0; m < 4; m++)
#pragma unroll
    for (int n = 0; n < 2; n++)
#pragma unroll
      for (int kk = 0; kk < 2; kk++)
        acc[MR + m][NC + n] = MFMA16(af[m][kk], bf[n][kk], acc[MR + m][NC + n]);
}
__device__ __forceinline__ void ph_begin() {
  __builtin_amdgcn_s_barrier();
  asm volatile("s_waitcnt lgkmcnt(0)" ::: "memory");
  __builtin_amdgcn_sched_barrier(0);
  __builtin_amdgcn_s_setprio(1);
}
template <int VMn>
__device__ __forceinline__ void ph_end() {
  __builtin_amdgcn_s_setprio(0);
  if constexpr (VMn == 8) asm volatile("s_waitcnt vmcnt(8)" ::: "memory");
  else if constexpr (VMn == 6) asm volatile("s_waitcnt vmcnt(6)" ::: "memory");
  else if constexpr (VMn == 4) asm volatile("s_waitcnt vmcnt(4)" ::: "memory");
  else if constexpr (VMn == 2) asm volatile("s_waitcnt vmcnt(2)" ::: "memory");
  else if constexpr (VMn == 0) asm volatile("s_waitcnt vmcnt(0)" ::: "memory");
  __builtin_amdgcn_s_barrier();
}
__device__ __forceinline__ void st2(const char* p0, const char* p1, int off,
                                    char* lds, int dst, int woff) {
  g2l16(p0 + off, lds + dst + woff);
  g2l16(p1 + off, lds + dst + 8192 + woff);
}

__device__ __forceinline__ void gemm256_core(const u16* __restrict__ A,
                                             const u16* __restrict__ Bm,
                                             int row0, int col0, char* lds,
                                             f32x4 (&acc)[8][4], int tid) {
  const int lane = tid & 63, w = tid >> 6;
  const int wr = w >> 2, wc = w & 3;
  const int l15 = lane & 15, l4 = lane >> 4;
  const int l7 = l15 & 7;
  int abase[2], bbase[2];
#pragma unroll
  for (int kk = 0; kk < 2; kk++) {
    int swz = ((kk * 4 + l4) ^ l7) << 4;
    abase[kk] = wr * 8192 + l15 * 128 + swz;
    bbase[kk] = 65536 + wc * 4096 + l15 * 128 + swz;
  }
  // per-lane staging base pointers (half/k offsets are additive constants:
  // A: half*131072 + kbytes; B: half*65536 + kbytes)
  const int sub0 = tid >> 3, sl0 = tid & 7;
  const int sub1 = (512 + tid) >> 3, sl1 = tid & 7;  // (512+tid)&7 == tid&7
  const int woff = w * 1024;
  const char* pa0 = (const char*)A + (size_t)row0 * 2048 +
      (size_t)((sub0 & 63) | ((sub0 & 64) << 1)) * 2048 + (sl0 ^ (sub0 & 7)) * 16;
  const char* pa1 = (const char*)A + (size_t)row0 * 2048 +
      (size_t)((sub1 & 63) | ((sub1 & 64) << 1)) * 2048 + (sl1 ^ (sub1 & 7)) * 16;
  const char* pb0 = (const char*)Bm + (size_t)col0 * 2048 +
      (size_t)((sub0 & 31) | ((sub0 & 0x60) << 1)) * 2048 + (sl0 ^ (sub0 & 7)) * 16;
  const char* pb1 = (const char*)Bm + (size_t)col0 * 2048 +
      (size_t)((sub1 & 31) | ((sub1 & 0x60) << 1)) * 2048 + (sl1 ^ (sub1 & 7)) * 16;

  bf16x8 afA[4][2], afC[4][2], bfB[2][2];

  // prologue: A0,B0,A1,B1 of tile0 (buf0, k=0); B0,A1 of tile1 (buf1, k=128B)
  st2(pa0, pa1, 0, lds, 0, woff);                    // A0[0]
  st2(pb0, pb1, 0, lds, 65536, woff);                // B0[0]
  st2(pa0, pa1, 131072, lds, 16384, woff);           // A1[0]
  st2(pb0, pb1, 65536, lds, 65536 + 16384, woff);    // B1[0]
  st2(pb0, pb1, 128, lds, 65536 + 32768, woff);      // B0[1]
  st2(pa0, pa1, 131072 + 128, lds, 49152, woff);     // A1[1]
  asm volatile("s_waitcnt vmcnt(0)" ::: "memory");
  __builtin_amdgcn_s_barrier();

  for (int u = 0; u < 7; ++u) {
    const int kB = u * 256;  // bytes; tile e=2u at kB, o at kB+128, etc.
    // P1[e]: rd A0->afA, B0->bfB ; st A0[o] ; q00
    rdAf<0>(lds, abase, afA);
    rdBf<0>(lds, bbase, bfB);
    st2(pa0, pa1, kB + 128, lds, 32768, woff);
    ph_begin(); mq(acc, afA, bfB, 0, 0); ph_end<-1>();
    // P2[e]: rd A1->afC ; st B1[o] ; q10
    rdAf<16384>(lds, abase, afC);
    st2(pb0, pb1, 65536 + kB + 128, lds, 65536 + 49152, woff);
    ph_begin(); mq(acc, afC, bfB, 4, 0); ph_end<-1>();
    // P3[e]: rd B1->bfB ; st B0[e+2], A1[e+2] ; q11+q01 ; vm(6)
    rdBf<16384>(lds, bbase, bfB);
    st2(pb0, pb1, kB + 256, lds, 65536, woff);
    st2(pa0, pa1, 131072 + kB + 256, lds, 16384, woff);
    ph_begin(); mq(acc, afC, bfB, 4, 2); mq(acc, afA, bfB, 0, 2); ph_end<6>();
    // P4[o]: rd A0->afA, B0->bfB ; st A0[e+2] ; q00
    rdAf<32768>(lds, abase, afA);
    rdBf<32768>(lds, bbase, bfB);
    st2(pa0, pa1, kB + 256, lds, 0, woff);
    ph_begin(); mq(acc, afA, bfB, 0, 0); ph_end<-1>();
    // P5[o]: rd A1->afC ; st B1[e+2] ; q10 ; vm(8)
    rdAf<49152>(lds, abase, afC);
    st2(pb0, pb1, 65536 + kB + 256, lds, 65536 + 16384, woff);
    ph_begin(); mq(acc, afC, bfB, 4, 0); ph_end<8>();
    // P6[o]: rd B1->bfB ; st B0[o+2], A1[o+2] ; q11+q01 ; vm(4)
    rdBf<49152>(lds, bbase, bfB);
    st2(pb0, pb1, kB + 384, lds, 65536 + 32768, woff);
    st2(pa0, pa1, 131072 + kB + 384, lds, 49152, woff);
    ph_begin(); mq(acc, afC, bfB, 4, 2); mq(acc, afA, bfB, 0, 2); ph_end<4>();
  }
  {  // epilogue: tiles 14 (buf0, kB=1792) and 15 (buf1, kB=1920)
    // P1: rd A0,B0[14] ; st A0[15] ; q00
    rdAf<0>(lds, abase, afA);
    rdBf<0>(lds, bbase, bfB);
    st2(pa0, pa1, 1792 + 128, lds, 32768, woff);
    ph_begin(); mq(acc, afA, bfB, 0, 0); ph_end<-1>();
    // P2: rd A1[14] ; st B1[15] ; q10
    rdAf<16384>(lds, abase, afC);
    st2(pb0, pb1, 65536 + 1792 + 128, lds, 65536 + 49152, woff);
    ph_begin(); mq(acc, afC, bfB, 4, 0); ph_end<-1>();
    // P3: rd B1[14] ; q11+q01 ; vm(2) [drains residual B0/A1[15] + A0[15]]
    rdBf<16384>(lds, bbase, bfB);
    ph_begin(); mq(acc, afC, bfB, 4, 2); mq(acc, afA, bfB, 0, 2); ph_end<2>();
    // P4: rd A0,B0[15] ; q00
    rdAf<32768>(lds, abase, afA);
    rdBf<32768>(lds, bbase, bfB);
    ph_begin(); mq(acc, afA, bfB, 0, 0); ph_end<-1>();
    // P5: rd A1[15] ; q10 ; vm(0) [drains B1[15]]
    rdAf<49152>(lds, abase, afC);
    ph_begin(); mq(acc, afC, bfB, 4, 0); ph_end<0>();
    // P6: rd B1[15] ; q11+q01
    rdBf<49152>(lds, bbase, bfB);
    ph_begin(); mq(acc, afC, bfB, 4, 2); mq(acc, afA, bfB, 0, 2); ph_end<-1>();
  }
}

// ---------------- QKV GEMM: [32768x1024] x [3072x1024]^T ----------------
__global__ __launch_bounds__(512, 2) void k_gemm_qkv(
    const u16* __restrict__ A, const u16* __restrict__ Bm,
    const float* __restrict__ bq, const float* __restrict__ bk,
    const float* __restrict__ bv, u16* __restrict__ Qb, u16* __restrict__ Kb,
    u16* __restrict__ Vb) {
  __shared__ char lds[131072];
  const int tid = threadIdx.x;
  const int lane = tid & 63, w = tid >> 6;
  const int wr = w >> 2, wc = w & 3;
  const int l15 = lane & 15, l4 = lane >> 4;
  int f = blockIdx.x;
  int swz = (f & 7) * 192 + (f >> 3);
  int bcol = swz % 12, brow = swz / 12;
  const int row0 = brow * 256, col0 = bcol * 256;
  f32x4 acc[8][4] = {};
  gemm256_core(A, Bm, row0, col0, lds, acc, tid);
  // ---- coalesced epilogue via LDS bounce (wave-private 16KB region) ----
  char* eb = lds + w * 16384;
  const int colW = col0 + wc * 64;
  const int sel = colW >> 10, hd = colW & 1023;
  const int h = hd >> 6;
  const float* bp = (sel == 0) ? bq : (sel == 1) ? bk : bv;
  const float* biasW = bp + hd;
  u16* dstW = (sel == 0) ? Qb : (sel == 1) ? Kb : Vb;
#pragma unroll
  for (int r = 0; r < 4; r++) {
#pragma unroll
    for (int mm = 0; mm < 2; mm++) {
      int mf = r * 2 + mm;
#pragma unroll
      for (int nf = 0; nf < 4; nf++)
#pragma unroll
        for (int j = 0; j < 4; j++) {
          int rowl = mm * 16 + l4 * 4 + j;
          *(float*)(eb + rowl * 272 + (nf * 16 + l15) * 4) = acc[mf][nf][j];
        }
    }
    asm volatile("s_waitcnt lgkmcnt(0)" ::: "memory");
    __builtin_amdgcn_sched_barrier(0);
#pragma unroll
    for (int it = 0; it < 4; it++) {
      int u = it * 64 + lane;
      int rowl = u >> 3, ch = u & 7;
      float4 a0 = *(const float4*)(eb + rowl * 272 + ch * 32);
      float4 a1 = *(const float4*)(eb + rowl * 272 + ch * 32 + 16);
      float4 b0 = *(const float4*)(biasW + ch * 8);
      float4 b1 = *(const float4*)(biasW + ch * 8 + 4);
      uint4 pk;
      pk.x = (u32)f2bf(a0.x + b0.x) | ((u32)f2bf(a0.y + b0.y) << 16);
      pk.y = (u32)f2bf(a0.z + b0.z) | ((u32)f2bf(a0.w + b0.w) << 16);
      pk.z = (u32)f2bf(a1.x + b1.x) | ((u32)f2bf(a1.y + b1.y) << 16);
      pk.w = (u32)f2bf(a1.z + b1.z) | ((u32)f2bf(a1.w + b1.w) << 16);
      int row = row0 + wr * 128 + r * 32 + rowl;
      int b = row >> 6, t = row & 63;
      *(uint4*)(dstW + ((size_t)(b * 16 + h)) * 4096 + t * 64 + ch * 8) = pk;
    }
    asm volatile("s_waitcnt lgkmcnt(0)" ::: "memory");
    __builtin_amdgcn_sched_barrier(0);
  }
}

// ---------------- output GEMM: [32768x1024] x [1024x1024]^T + bias -> fp32 --
__global__ __launch_bounds__(512, 2) void k_gemm_out(
    const u16* __restrict__ A, const u16* __restrict__ Bm,
    const float* __restrict__ bo, float* __restrict__ out) {
  __shared__ char lds[131072];
  const int tid = threadIdx.x;
  const int lane = tid & 63, w = tid >> 6;
  const int wr = w >> 2, wc = w & 3;
  const int l15 = lane & 15, l4 = lane >> 4;
  int f = blockIdx.x;  // 512 blocks = 8 chunks of 64, col-fastest
  int swz = (f & 7) * 64 + (f >> 3);
  int bcol = swz & 3, brow = swz >> 2;
  const int row0 = brow * 256, col0 = bcol * 256;
  f32x4 acc[8][4] = {};
  gemm256_core(A, Bm, row0, col0, lds, acc, tid);
  // ---- coalesced epilogue via LDS bounce ----
  char* eb = lds + w * 16384;
  const int colW = col0 + wc * 64;
  const float* biasW = bo + colW;
#pragma unroll
  for (int r = 0; r < 4; r++) {
#pragma unroll
    for (int mm = 0; mm < 2; mm++) {
      int mf = r * 2 + mm;
#pragma unroll
      for (int nf = 0; nf < 4; nf++)
#pragma unroll
        for (int j = 0; j < 4; j++) {
          int rowl = mm * 16 + l4 * 4 + j;
          *(float*)(eb + rowl * 272 + (nf * 16 + l15) * 4) = acc[mf][nf][j];
        }
    }
    asm volatile("s_waitcnt lgkmcnt(0)" ::: "memory");
    __builtin_amdgcn_sched_barrier(0);
#pragma unroll
    for (int it = 0; it < 8; it++) {
      int u = it * 64 + lane;
      int rowl = u >> 4, ch = u & 15;
      float4 a0 = *(const float4*)(eb + rowl * 272 + ch * 16);
      float4 b0 = *(const float4*)(biasW + ch * 4);
      a0.x += b0.x; a0.y += b0.y; a0.z += b0.z; a0.w += b0.w;
      int row = row0 + wr * 128 + r * 32 + rowl;
      *(float4*)(out + (size_t)row * 1024 + colW + ch * 4) = a0;
    }
    asm volatile("s_waitcnt lgkmcnt(0)" ::: "memory");
    __builtin_amdgcn_sched_barrier(0);
  }
}

// ---------------- bias1[b,h,t,s] = sum_d q[b,h,t,d]*rel_k[h,idx[t,s],d] + T3
__global__ __launch_bounds__(256) void k_bias1(
    const u16* __restrict__ Qb, const u16* __restrict__ relq,
    const u16* __restrict__ relk, const int* __restrict__ relidx,
    u16* __restrict__ bias1) {
  const int tid = threadIdx.x, lane = tid & 63, w = tid >> 6;
  const int l15 = lane & 15, l4 = lane >> 4;
  const int t = blockIdx.x, h = blockIdx.y, bc = blockIdx.z;
  __shared__ char lds[16640];
  char* RK = lds;
  char* RQ = lds + 8192;
  float* T3 = (float*)(lds + 16384);
#pragma unroll
  for (int c = 0; c < 2; c++) {
    int ch = c * 256 + tid;
    int sr = ch >> 3, sl = (ch & 7) ^ (sr & 7);
    int ri = relidx[t * 64 + sr];
    size_t so = ((size_t)h * 225 + ri) * 64 + sl * 8;
    g2l16(relk + so, RK + c * 4096 + w * 1024);
    g2l16(relq + so, RQ + c * 4096 + w * 1024);
  }
  __syncthreads();
  if (tid < 64) {
    int sr = tid;
    float sum = 0.f;
#pragma unroll
    for (int sl = 0; sl < 8; sl++) {
      int o = sr * 128 + ((sl ^ (sr & 7)) << 4);
      bf16x8 aq = *(const bf16x8*)(RQ + o);
      bf16x8 ak = *(const bf16x8*)(RK + o);
#pragma unroll
      for (int j = 0; j < 8; j++) sum += (float)aq[j] * (float)ak[j];
    }
    T3[sr] = sum;
  }
  bf16x8 bfr[4][2];
#pragma unroll
  for (int n = 0; n < 4; n++)
#pragma unroll
    for (int kh = 0; kh < 2; kh++) {
      int r = n * 16 + l15;
      int sl = ((kh << 2) + l4) ^ (r & 7);
      bfr[n][kh] = *(const bf16x8*)(RK + r * 128 + sl * 16);
    }
  __syncthreads();
  f32x4 acc[4][4] = {};
#pragma unroll
  for (int m = 0; m < 4; m++) {
    int bb = bc * 256 + w * 64 + m * 16 + l15;
    const u16* ap = Qb + ((size_t)(bb * 16 + h)) * 4096 + t * 64 + l4 * 8;
    bf16x8 a0 = *(const bf16x8*)ap;
    bf16x8 a1 = *(const bf16x8*)(ap + 32);
#pragma unroll
    for (int n = 0; n < 4; n++) {
      acc[m][n] = MFMA16(a0, bfr[n][0], acc[m][n]);
      acc[m][n] = MFMA16(a1, bfr[n][1], acc[m][n]);
    }
  }
#pragma unroll
  for (int m = 0; m < 4; m++)
#pragma unroll
    for (int n = 0; n < 4; n++)
#pragma unroll
      for (int j = 0; j < 4; j++) {
        int bb = bc * 256 + w * 64 + m * 16 + l4 * 4 + j;
        int s_ = n * 16 + l15;
        bias1[((size_t)(bb * 16 + h)) * 4096 + t * 64 + s_] =
            f2bf(acc[m][n][j] + T3[s_]);
      }
}

// ---------------- bias2[b,h,s,t] = sum_d rel_q[h,idx[t,s],d]*k[b,h,s,d]
__global__ __launch_bounds__(256) void k_bias2(
    const u16* __restrict__ Kb, const u16* __restrict__ relq,
    const int* __restrict__ relidx, u16* __restrict__ bias2) {
  const int tid = threadIdx.x, lane = tid & 63, w = tid >> 6;
  const int l15 = lane & 15, l4 = lane >> 4;
  const int s = blockIdx.x, h = blockIdx.y, bc = blockIdx.z;
  __shared__ char lds[8192];
#pragma unroll
  for (int c = 0; c < 2; c++) {
    int ch = c * 256 + tid;
    int tq = ch >> 3, sl = (ch & 7) ^ (tq & 7);
    int ri = relidx[tq * 64 + s];
    g2l16(relq + ((size_t)h * 225 + ri) * 64 + sl * 8,
          lds + c * 4096 + w * 1024);
  }
  __syncthreads();
  bf16x8 bfr[4][2];
#pragma unroll
  for (int n = 0; n < 4; n++)
#pragma unroll
    for (int kh = 0; kh < 2; kh++) {
      int r = n * 16 + l15;
      int sl = ((kh << 2) + l4) ^ (r & 7);
      bfr[n][kh] = *(const bf16x8*)(lds + r * 128 + sl * 16);
    }
  f32x4 acc[4][4] = {};
#pragma unroll
  for (int m = 0; m < 4; m++) {
    int bb = bc * 256 + w * 64 + m * 16 + l15;
    const u16* ap = Kb + ((size_t)(bb * 16 + h)) * 4096 + s * 64 + l4 * 8;
    bf16x8 a0 = *(const bf16x8*)ap;
    bf16x8 a1 = *(const bf16x8*)(ap + 32);
#pragma unroll
    for (int n = 0; n < 4; n++) {
      acc[m][n] = MFMA16(a0, bfr[n][0], acc[m][n]);
      acc[m][n] = MFMA16(a1, bfr[n][1], acc[m][n]);
    }
  }
#pragma unroll
  for (int m = 0; m < 4; m++)
#pragma unroll
    for (int n = 0; n < 4; n++)
#pragma unroll
      for (int j = 0; j < 4; j++) {
        int bb = bc * 256 + w * 64 + m * 16 + l4 * 4 + j;
        int tcol = n * 16 + l15;
        bias2[((size_t)(bb * 16 + h)) * 4096 + s * 64 + tcol] =
            f2bf(acc[m][n][j]);
      }
}

// ---------------- attention per (b,h): S=QK^T + b1 + b2^T, softmax, P, PV ----
__global__ __launch_bounds__(256) void k_attn(
    const u16* __restrict__ Qb, const u16* __restrict__ Kb,
    const u16* __restrict__ Vb, const u16* __restrict__ b1g,
    const u16* __restrict__ b2g, u16* __restrict__ Pg,
    u16* __restrict__ aout) {
  const int tid = threadIdx.x, lane = tid & 63, w = tid >> 6;
  const int l15 = lane & 15, l4 = lane >> 4;
  const int b = blockIdx.x, h = blockIdx.y;
  __shared__ char lds[49152];
  char* Qt = lds;
  char* Kt = lds + 8192;
  char* Vt = lds + 16384;  // natural [s][d] layout
  char* B1 = lds + 24576;
  char* B2 = lds + 32768;
  char* Pt = lds + 40960;
  const size_t base = ((size_t)(b * 16 + h)) * 4096;
#pragma unroll
  for (int c = 0; c < 2; c++) {
    int ch = c * 256 + tid;
    int r = ch >> 3, sl = (ch & 7) ^ (r & 7);
    size_t so = base + r * 64 + sl * 8;
    int dst = c * 4096 + w * 1024;
    g2l16(Qb + so, Qt + dst);
    g2l16(Kb + so, Kt + dst);
    g2l16(Vb + so, Vt + dst);
    g2l16(b1g + so, B1 + dst);
    g2l16(b2g + so, B2 + dst);
  }
  __syncthreads();
  // S = Q K^T, wave w owns rows [w*16, w*16+16)
  f32x4 acc[4] = {};
  bf16x8 qf[2];
  {
    int r = w * 16 + l15;
#pragma unroll
    for (int kh = 0; kh < 2; kh++) {
      int sl = ((kh << 2) + l4) ^ (r & 7);
      qf[kh] = *(const bf16x8*)(Qt + r * 128 + sl * 16);
    }
  }
#pragma unroll
  for (int n = 0; n < 4; n++) {
    int r = n * 16 + l15;
#pragma unroll
    for (int kh = 0; kh < 2; kh++) {
      int sl = ((kh << 2) + l4) ^ (r & 7);
      bf16x8 kf = *(const bf16x8*)(Kt + r * 128 + sl * 16);
      acc[n] = MFMA16(qf[kh], kf, acc[n]);
    }
  }
  const int t0 = w * 16 + l4 * 4;
#pragma unroll
  for (int j = 0; j < 4; j++) {
    int t_ = t0 + j;
    float lv[4];
#pragma unroll
    for (int n = 0; n < 4; n++) {
      int s_ = n * 16 + l15;
      float x = acc[n][j];
      x += bf2f(*(const u16*)(B1 + t_ * 128 + ((s_ * 2) ^ ((t_ & 7) << 4))));
      x += bf2f(*(const u16*)(B2 + s_ * 128 + ((t_ * 2) ^ ((s_ & 7) << 4))));
      lv[n] = x * 0.125f;
    }
    float mx = fmaxf(fmaxf(lv[0], lv[1]), fmaxf(lv[2], lv[3]));
#pragma unroll
    for (int d = 1; d < 16; d <<= 1) mx = fmaxf(mx, __shfl_xor(mx, d, 64));
    float e0 = __expf(lv[0] - mx), e1 = __expf(lv[1] - mx);
    float e2 = __expf(lv[2] - mx), e3 = __expf(lv[3] - mx);
    float sum = e0 + e1 + e2 + e3;
#pragma unroll
    for (int d = 1; d < 16; d <<= 1) sum += __shfl_xor(sum, d, 64);
    float inv = 1.0f / sum;
    float pe[4] = {e0 * inv, e1 * inv, e2 * inv, e3 * inv};
#pragma unroll
    for (int n = 0; n < 4; n++) {
      int s_ = n * 16 + l15;
      *(u16*)(Pt + t_ * 128 + ((s_ * 2) ^ ((t_ & 7) << 4))) = f2bf(pe[n]);
    }
  }
  __syncthreads();
  // P -> global (linearized, undo swizzle)
#pragma unroll
  for (int c = 0; c < 2; c++) {
    int ch = c * 256 + tid;
    int r = ch >> 3, sl = ch & 7;
    uint4 v = *(const uint4*)(Pt + r * 128 + ((sl ^ (r & 7)) << 4));
    *((uint4*)(Pg + base) + ch) = v;
  }
  // out_v = P * V; V is [s][d] -> B-frags via scalar column gather
  f32x4 acc2[4] = {};
  bf16x8 pf[2];
  {
    int r = w * 16 + l15;
#pragma unroll
    for (int kh = 0; kh < 2; kh++) {
      int sl = ((kh << 2) + l4) ^ (r & 7);
      pf[kh] = *(const bf16x8*)(Pt + r * 128 + sl * 16);
    }
  }
#pragma unroll
  for (int n = 0; n < 4; n++) {
#pragma unroll
    for (int kh = 0; kh < 2; kh++) {
      bf16x8 tmp;
#pragma unroll
      for (int j = 0; j < 8; j++) {
        int s_ = (kh << 5) + (l4 << 3) + j;
        int d_ = n * 16 + l15;
        u16 uu = *(const u16*)(Vt + s_ * 128 + ((d_ * 2) ^ ((s_ & 7) << 4)));
        tmp[j] = __builtin_bit_cast(__bf16, uu);
      }
      acc2[n] = MFMA16(pf[kh], tmp, acc2[n]);
    }
  }
#pragma unroll
  for (int n = 0; n < 4; n++)
#pragma unroll
    for (int j = 0; j < 4; j++) {
      int t_ = t0 + j, d_ = n * 16 + l15;
      aout[((size_t)(b * 64 + t_)) * 1024 + h * 64 + d_] = f2bf(acc2[n][j]);
    }
}

// ---------------- out_relv: aout[b,t,h,d] += sum_s P[b,s]*rel_v[h,idx[t,s],d]
__global__ __launch_bounds__(256) void k_relv(
    const u16* __restrict__ Pg, const u16* __restrict__ relv,
    const int* __restrict__ relidx, u16* __restrict__ aout) {
  const int tid = threadIdx.x, lane = tid & 63, w = tid >> 6;
  const int l15 = lane & 15, l4 = lane >> 4;
  const int t = blockIdx.x, h = blockIdx.y, bc = blockIdx.z;
  __shared__ char lds[8192];
#pragma unroll
  for (int c = 0; c < 2; c++) {
    int ch = c * 256 + tid;
    int sr = ch >> 3, sl = (ch & 7) ^ (sr & 7);
    int ri = relidx[t * 64 + sr];
    g2l16(relv + ((size_t)h * 225 + ri) * 64 + sl * 8,
          lds + c * 4096 + w * 1024);
  }
  __syncthreads();
  bf16x8 bfr[4][2];
#pragma unroll
  for (int n = 0; n < 4; n++)
#pragma unroll
    for (int kh = 0; kh < 2; kh++) {
      bf16x8 tmp;
#pragma unroll
      for (int j = 0; j < 8; j++) {
        int s_ = (kh << 5) + (l4 << 3) + j;
        int d_ = n * 16 + l15;
        u16 u = *(const u16*)(lds + s_ * 128 + ((d_ * 2) ^ ((s_ & 7) << 4)));
        tmp[j] = __builtin_bit_cast(__bf16, u);
      }
      bfr[n][kh] = tmp;
    }
  f32x4 acc[4][4] = {};
#pragma unroll
  for (int m = 0; m < 4; m++) {
    int bb = bc * 256 + w * 64 + m * 16 + l15;
    const u16* ap = Pg + ((size_t)(bb * 16 + h)) * 4096 + t * 64 + l4 * 8;
    bf16x8 a0 = *(const bf16x8*)ap;
    bf16x8 a1 = *(const bf16x8*)(ap + 32);
#pragma unroll
    for (int n = 0; n < 4; n++) {
      acc[m][n] = MFMA16(a0, bfr[n][0], acc[m][n]);
      acc[m][n] = MFMA16(a1, bfr[n][1], acc[m][n]);
    }
  }
#pragma unroll
  for (int m = 0; m < 4; m++)
#pragma unroll
    for (int n = 0; n < 4; n++)
#pragma unroll
      for (int j = 0; j < 4; j++) {
        int bb = bc * 256 + w * 64 + m * 16 + l4 * 4 + j;
        int d_ = n * 16 + l15;
        size_t o = ((size_t)(bb * 64 + t)) * 1024 + h * 64 + d_;
        aout[o] = f2bf(bf2f(aout[o]) + acc[m][n][j]);
      }
}

extern "C" void kernel_launch(void* const* d_in, const int* in_sizes, int n_in,
                              void* d_out, int out_size, void* d_ws,
                              size_t ws_size, hipStream_t stream) {
  const float* x = (const float*)d_in[0];
  const float* Wq = (const float*)d_in[1];
  const float* bq = (const float*)d_in[2];
  const float* Wk = (const float*)d_in[3];
  const float* bk = (const float*)d_in[4];
  const float* Wv = (const float*)d_in[5];
  const float* bv = (const float*)d_in[6];
  const float* Wo = (const float*)d_in[7];
  const float* bo = (const float*)d_in[8];
  const float* rq = (const float*)d_in[9];
  const float* rk = (const float*)d_in[10];
  const float* rv = (const float*)d_in[11];
  const int* ridx = (const int*)d_in[12];
  float* out = (float*)d_out;

  char* ws = (char*)d_ws;
  const size_t MB = 1ull << 20;
  u16* xb = (u16*)(ws + 0);  // reused as P after k_gemm_qkv consumes it
  u16* Qb = (u16*)(ws + 64 * MB);
  u16* Kb = (u16*)(ws + 128 * MB);
  u16* Vb = (u16*)(ws + 192 * MB);
  u16* b1 = (u16*)(ws + 256 * MB);
  u16* b2 = (u16*)(ws + 320 * MB);
  u16* aout = (u16*)(ws + 384 * MB);
  u16* wqkv = (u16*)(ws + 448 * MB);
  u16* wo = (u16*)(ws + 454 * MB);
  u16* relq = (u16*)(ws + 456 * MB);
  u16* relk = (u16*)(ws + 457 * MB);
  u16* relv = (u16*)(ws + 458 * MB);
  u16* Pg = xb;

  k_cvt<<<32768, 256, 0, stream>>>(x, xb, 8388608);
  k_cvt<<<1024, 256, 0, stream>>>(Wq, wqkv, 262144);
  k_cvt<<<1024, 256, 0, stream>>>(Wk, wqkv + 1048576, 262144);
  k_cvt<<<1024, 256, 0, stream>>>(Wv, wqkv + 2097152, 262144);
  k_cvt<<<1024, 256, 0, stream>>>(Wo, wo, 262144);
  k_cvt<<<225, 256, 0, stream>>>(rq, relq, 57600);
  k_cvt<<<225, 256, 0, stream>>>(rk, relk, 57600);
  k_cvt<<<225, 256, 0, stream>>>(rv, relv, 57600);

  k_gemm_qkv<<<1536, 512, 0, stream>>>(xb, wqkv, bq, bk, bv, Qb, Kb, Vb);
  k_bias1<<<dim3(64, 16, 2), 256, 0, stream>>>(Qb, relq, relk, ridx, b1);
  k_bias2<<<dim3(64, 16, 2), 256, 0, stream>>>(Kb, relq, ridx, b2);
  k_attn<<<dim3(512, 16), 256, 0, stream>>>(Qb, Kb, Vb, b1, b2, Pg, aout);
  k_relv<<<dim3(64, 16, 2), 256, 0, stream>>>(Pg, relv, ridx, aout);
  k_gemm_out<<<512, 512, 0, stream>>>(aout, wo, bo, out);
}

// Round 8
// 534.398 us; speedup vs baseline: 1.1709x; 1.0010x over previous
//
#include <hip/hip_runtime.h>
#include <cstdint>

// ChessRelativeTransformer on MI355X (gfx950), bf16 MFMA pipeline.
// B=512 T=64 H=16 DH=64 D=1024 NUM_REL=225 scale=0.125
// R8: intra-phase kk-pipelining in the 6-phase GEMM core: per phase issue
//     kk0 reads then kk1 reads, wait lgkmcnt(<kk1 cnt>) (counted, in-order),
//     MFMA kk0 overlaps LDS service of kk1, then lgkmcnt(0) + MFMA kk1.
//     Stage placement / vmcnt ledger byte-identical to R7 (proven).

typedef unsigned short u16;
typedef unsigned int u32;
typedef __bf16 bf16x8 __attribute__((ext_vector_type(8)));
typedef float f32x4 __attribute__((ext_vector_type(4)));

#define MFMA16(a, b, c) __builtin_amdgcn_mfma_f32_16x16x32_bf16(a, b, c, 0, 0, 0)
#define BAR __builtin_amdgcn_s_barrier()
#define SB __builtin_amdgcn_sched_barrier(0)
#define LGK(n) do { asm volatile("s_waitcnt lgkmcnt(" #n ")" ::: "memory"); SB; } while (0)
#define VMC(n) asm volatile("s_waitcnt vmcnt(" #n ")" ::: "memory")

__device__ __forceinline__ u16 f2bf(float f) {
  u32 u = __builtin_bit_cast(u32, f);
  u = (u + 0x7FFFu + ((u >> 16) & 1u)) >> 16;
  return (u16)u;
}
__device__ __forceinline__ float bf2f(u16 h) {
  return __builtin_bit_cast(float, ((u32)h) << 16);
}

__device__ __forceinline__ void g2l16(const void* g, void* lds_wave_base) {
#if __has_builtin(__builtin_amdgcn_global_load_lds)
  __builtin_amdgcn_global_load_lds(
      (const __attribute__((address_space(1))) u32*)(uintptr_t)g,
      (__attribute__((address_space(3))) u32*)(uintptr_t)lds_wave_base, 16, 0, 0);
#else
  uint4 v = *(const uint4*)g;
  *(uint4*)((char*)lds_wave_base + (threadIdx.x & 63) * 16) = v;
#endif
}

// ---------------- fp32 -> bf16 convert (4 elems/thread) ----------------
__global__ __launch_bounds__(256) void k_cvt(const float* __restrict__ src,
                                             u16* __restrict__ dst, int nq) {
  int i = blockIdx.x * 256 + threadIdx.x;
  if (i >= nq) return;
  float4 v = ((const float4*)src)[i];
  ushort4 o;
  o.x = f2bf(v.x); o.y = f2bf(v.y); o.z = f2bf(v.z); o.w = f2bf(v.w);
  ((ushort4*)dst)[i] = o;
}

// ================= 256x256 6-phase GEMM core (R8: kk-pipelined) ============
// C = A * Bm^T. 512 thr = 8 waves (2M x 4N), BK=64, 128KiB dbuf LDS.
// LDS map: A half at (buf*2+half)*16384; B at 65536 + same.

template <int OFF, int KK>
__device__ __forceinline__ void rdAk(const char* lds, const int* abase,
                                     bf16x8 (&f)[4]) {
#pragma unroll
  for (int m = 0; m < 4; m++)
    f[m] = *(const bf16x8*)(lds + abase[KK] + OFF + m * 2048);
}
template <int OFF, int KK>
__device__ __forceinline__ void rdBk(const char* lds, const int* bbase,
                                     bf16x8 (&f)[2]) {
#pragma unroll
  for (int n = 0; n < 2; n++)
    f[n] = *(const bf16x8*)(lds + bbase[KK] + OFF + n * 2048);
}
__device__ __forceinline__ void mq8(f32x4 (&acc)[8][4], const bf16x8 (&af)[4],
                                    const bf16x8 (&bf)[2], int MR, int NC) {
#pragma unroll
  for (int m = 0; m < 4; m++)
#pragma unroll
    for (int n = 0; n < 2; n++)
      acc[MR + m][NC + n] = MFMA16(af[m], bf[n], acc[MR + m][NC + n]);
}
__device__ __forceinline__ void st2(const char* p0, const char* p1, int off,
                                    char* lds, int dst, int woff) {
  g2l16(p0 + off, lds + dst + woff);
  g2l16(p1 + off, lds + dst + 8192 + woff);
}

__device__ __forceinline__ void gemm256_core(const u16* __restrict__ A,
                                             const u16* __restrict__ Bm,
                                             int row0, int col0, char* lds,
                                             f32x4 (&acc)[8][4], int tid) {
  const int lane = tid & 63, w = tid >> 6;
  const int wr = w >> 2, wc = w & 3;
  const int l15 = lane & 15, l4 = lane >> 4;
  const int l7 = l15 & 7;
  int abase[2], bbase[2];
#pragma unroll
  for (int kk = 0; kk < 2; kk++) {
    int swz = ((kk * 4 + l4) ^ l7) << 4;
    abase[kk] = wr * 8192 + l15 * 128 + swz;
    bbase[kk] = 65536 + wc * 4096 + l15 * 128 + swz;
  }
  const int sub0 = tid >> 3, sl0 = tid & 7;
  const int sub1 = (512 + tid) >> 3, sl1 = tid & 7;
  const int woff = w * 1024;
  const char* pa0 = (const char*)A + (size_t)row0 * 2048 +
      (size_t)((sub0 & 63) | ((sub0 & 64) << 1)) * 2048 + (sl0 ^ (sub0 & 7)) * 16;
  const char* pa1 = (const char*)A + (size_t)row0 * 2048 +
      (size_t)((sub1 & 63) | ((sub1 & 64) << 1)) * 2048 + (sl1 ^ (sub1 & 7)) * 16;
  const char* pb0 = (const char*)Bm + (size_t)col0 * 2048 +
      (size_t)((sub0 & 31) | ((sub0 & 0x60) << 1)) * 2048 + (sl0 ^ (sub0 & 7)) * 16;
  const char* pb1 = (const char*)Bm + (size_t)col0 * 2048 +
      (size_t)((sub1 & 31) | ((sub1 & 0x60) << 1)) * 2048 + (sl1 ^ (sub1 & 7)) * 16;

  bf16x8 afA0[4], afA1[4], afC0[4], afC1[4], bfB0[2], bfB1[2];

  // prologue: A0,B0,A1,B1 of tile0 (buf0); B0,A1 of tile1 (buf1)
  st2(pa0, pa1, 0, lds, 0, woff);                    // A0[0]
  st2(pb0, pb1, 0, lds, 65536, woff);                // B0[0]
  st2(pa0, pa1, 131072, lds, 16384, woff);           // A1[0]
  st2(pb0, pb1, 65536, lds, 65536 + 16384, woff);    // B1[0]
  st2(pb0, pb1, 128, lds, 65536 + 32768, woff);      // B0[1]
  st2(pa0, pa1, 131072 + 128, lds, 49152, woff);     // A1[1]
  VMC(0);
  BAR;

  for (int u = 0; u < 7; ++u) {
    const int kB = u * 256;
    // P1[e,q00]: rd A0,B0 ; st A0[o]
    rdAk<0, 0>(lds, abase, afA0); rdBk<0, 0>(lds, bbase, bfB0);
    rdAk<0, 1>(lds, abase, afA1); rdBk<0, 1>(lds, bbase, bfB1);
    st2(pa0, pa1, kB + 128, lds, 32768, woff);
    BAR; LGK(6);
    __builtin_amdgcn_s_setprio(1);
    mq8(acc, afA0, bfB0, 0, 0);
    LGK(0);
    mq8(acc, afA1, bfB1, 0, 0);
    __builtin_amdgcn_s_setprio(0);
    BAR;
    // P2[e,q10]: rd A1 ; st B1[o]
    rdAk<16384, 0>(lds, abase, afC0);
    rdAk<16384, 1>(lds, abase, afC1);
    st2(pb0, pb1, 65536 + kB + 128, lds, 65536 + 49152, woff);
    BAR; LGK(4);
    __builtin_amdgcn_s_setprio(1);
    mq8(acc, afC0, bfB0, 4, 0);
    LGK(0);
    mq8(acc, afC1, bfB1, 4, 0);
    __builtin_amdgcn_s_setprio(0);
    BAR;
    // P3[e,q11+q01]: rd B1 ; st B0[e+2], A1[e+2] ; vm(6)
    rdBk<16384, 0>(lds, bbase, bfB0);
    rdBk<16384, 1>(lds, bbase, bfB1);
    st2(pb0, pb1, kB + 256, lds, 65536, woff);
    st2(pa0, pa1, 131072 + kB + 256, lds, 16384, woff);
    BAR; LGK(2);
    __builtin_amdgcn_s_setprio(1);
    mq8(acc, afC0, bfB0, 4, 2); mq8(acc, afA0, bfB0, 0, 2);
    LGK(0);
    mq8(acc, afC1, bfB1, 4, 2); mq8(acc, afA1, bfB1, 0, 2);
    __builtin_amdgcn_s_setprio(0);
    VMC(6); BAR;
    // P4[o,q00]: rd A0,B0 ; st A0[e+2]
    rdAk<32768, 0>(lds, abase, afA0); rdBk<32768, 0>(lds, bbase, bfB0);
    rdAk<32768, 1>(lds, abase, afA1); rdBk<32768, 1>(lds, bbase, bfB1);
    st2(pa0, pa1, kB + 256, lds, 0, woff);
    BAR; LGK(6);
    __builtin_amdgcn_s_setprio(1);
    mq8(acc, afA0, bfB0, 0, 0);
    LGK(0);
    mq8(acc, afA1, bfB1, 0, 0);
    __builtin_amdgcn_s_setprio(0);
    BAR;
    // P5[o,q10]: rd A1 ; st B1[e+2] ; vm(8)
    rdAk<49152, 0>(lds, abase, afC0);
    rdAk<49152, 1>(lds, abase, afC1);
    st2(pb0, pb1, 65536 + kB + 256, lds, 65536 + 16384, woff);
    BAR; LGK(4);
    __builtin_amdgcn_s_setprio(1);
    mq8(acc, afC0, bfB0, 4, 0);
    LGK(0);
    mq8(acc, afC1, bfB1, 4, 0);
    __builtin_amdgcn_s_setprio(0);
    VMC(8); BAR;
    // P6[o,q11+q01]: rd B1 ; st B0[o+2], A1[o+2] ; vm(4)
    rdBk<49152, 0>(lds, bbase, bfB0);
    rdBk<49152, 1>(lds, bbase, bfB1);
    st2(pb0, pb1, kB + 384, lds, 65536 + 32768, woff);
    st2(pa0, pa1, 131072 + kB + 384, lds, 49152, woff);
    BAR; LGK(2);
    __builtin_amdgcn_s_setprio(1);
    mq8(acc, afC0, bfB0, 4, 2); mq8(acc, afA0, bfB0, 0, 2);
    LGK(0);
    mq8(acc, afC1, bfB1, 4, 2); mq8(acc, afA1, bfB1, 0, 2);
    __builtin_amdgcn_s_setprio(0);
    VMC(4); BAR;
  }
  {  // peeled final iteration (tiles 14,15): stage A0[15]@P1, B1[15]@P2;
     // drains P3 vm(2), P5 vm(0) (R7 ledger).
    // P1
    rdAk<0, 0>(lds, abase, afA0); rdBk<0, 0>(lds, bbase, bfB0);
    rdAk<0, 1>(lds, abase, afA1); rdBk<0, 1>(lds, bbase, bfB1);
    st2(pa0, pa1, 1792 + 128, lds, 32768, woff);
    BAR; LGK(6);
    mq8(acc, afA0, bfB0, 0, 0);
    LGK(0);
    mq8(acc, afA1, bfB1, 0, 0);
    BAR;
    // P2
    rdAk<16384, 0>(lds, abase, afC0);
    rdAk<16384, 1>(lds, abase, afC1);
    st2(pb0, pb1, 65536 + 1792 + 128, lds, 65536 + 49152, woff);
    BAR; LGK(4);
    mq8(acc, afC0, bfB0, 4, 0);
    LGK(0);
    mq8(acc, afC1, bfB1, 4, 0);
    BAR;
    // P3 ; vm(2)
    rdBk<16384, 0>(lds, bbase, bfB0);
    rdBk<16384, 1>(lds, bbase, bfB1);
    BAR; LGK(2);
    mq8(acc, afC0, bfB0, 4, 2); mq8(acc, afA0, bfB0, 0, 2);
    LGK(0);
    mq8(acc, afC1, bfB1, 4, 2); mq8(acc, afA1, bfB1, 0, 2);
    VMC(2); BAR;
    // P4
    rdAk<32768, 0>(lds, abase, afA0); rdBk<32768, 0>(lds, bbase, bfB0);
    rdAk<32768, 1>(lds, abase, afA1); rdBk<32768, 1>(lds, bbase, bfB1);
    BAR; LGK(6);
    mq8(acc, afA0, bfB0, 0, 0);
    LGK(0);
    mq8(acc, afA1, bfB1, 0, 0);
    BAR;
    // P5 ; vm(0)
    rdAk<49152, 0>(lds, abase, afC0);
    rdAk<49152, 1>(lds, abase, afC1);
    BAR; LGK(4);
    mq8(acc, afC0, bfB0, 4, 0);
    LGK(0);
    mq8(acc, afC1, bfB1, 4, 0);
    VMC(0); BAR;
    // P6
    rdBk<49152, 0>(lds, bbase, bfB0);
    rdBk<49152, 1>(lds, bbase, bfB1);
    BAR; LGK(2);
    mq8(acc, afC0, bfB0, 4, 2); mq8(acc, afA0, bfB0, 0, 2);
    LGK(0);
    mq8(acc, afC1, bfB1, 4, 2); mq8(acc, afA1, bfB1, 0, 2);
    BAR;
  }
}

// ---------------- QKV GEMM: [32768x1024] x [3072x1024]^T ----------------
__global__ __launch_bounds__(512, 2) void k_gemm_qkv(
    const u16* __restrict__ A, const u16* __restrict__ Bm,
    const float* __restrict__ bq, const float* __restrict__ bk,
    const float* __restrict__ bv, u16* __restrict__ Qb, u16* __restrict__ Kb,
    u16* __restrict__ Vb) {
  __shared__ char lds[131072];
  const int tid = threadIdx.x;
  const int lane = tid & 63, w = tid >> 6;
  const int wr = w >> 2, wc = w & 3;
  const int l15 = lane & 15, l4 = lane >> 4;
  int f = blockIdx.x;
  int swz = (f & 7) * 192 + (f >> 3);
  int bcol = swz % 12, brow = swz / 12;
  const int row0 = brow * 256, col0 = bcol * 256;
  f32x4 acc[8][4] = {};
  gemm256_core(A, Bm, row0, col0, lds, acc, tid);
  // ---- coalesced epilogue via LDS bounce (wave-private 16KB region) ----
  char* eb = lds + w * 16384;
  const int colW = col0 + wc * 64;
  const int sel = colW >> 10, hd = colW & 1023;
  const int h = hd >> 6;
  const float* bp = (sel == 0) ? bq : (sel == 1) ? bk : bv;
  const float* biasW = bp + hd;
  u16* dstW = (sel == 0) ? Qb : (sel == 1) ? Kb : Vb;
#pragma unroll
  for (int r = 0; r < 4; r++) {
#pragma unroll
    for (int mm = 0; mm < 2; mm++) {
      int mf = r * 2 + mm;
#pragma unroll
      for (int nf = 0; nf < 4; nf++)
#pragma unroll
        for (int j = 0; j < 4; j++) {
          int rowl = mm * 16 + l4 * 4 + j;
          *(float*)(eb + rowl * 272 + (nf * 16 + l15) * 4) = acc[mf][nf][j];
        }
    }
    LGK(0);
#pragma unroll
    for (int it = 0; it < 4; it++) {
      int u = it * 64 + lane;
      int rowl = u >> 3, ch = u & 7;
      float4 a0 = *(const float4*)(eb + rowl * 272 + ch * 32);
      float4 a1 = *(const float4*)(eb + rowl * 272 + ch * 32 + 16);
      float4 b0 = *(const float4*)(biasW + ch * 8);
      float4 b1 = *(const float4*)(biasW + ch * 8 + 4);
      uint4 pk;
      pk.x = (u32)f2bf(a0.x + b0.x) | ((u32)f2bf(a0.y + b0.y) << 16);
      pk.y = (u32)f2bf(a0.z + b0.z) | ((u32)f2bf(a0.w + b0.w) << 16);
      pk.z = (u32)f2bf(a1.x + b1.x) | ((u32)f2bf(a1.y + b1.y) << 16);
      pk.w = (u32)f2bf(a1.z + b1.z) | ((u32)f2bf(a1.w + b1.w) << 16);
      int row = row0 + wr * 128 + r * 32 + rowl;
      int b = row >> 6, t = row & 63;
      *(uint4*)(dstW + ((size_t)(b * 16 + h)) * 4096 + t * 64 + ch * 8) = pk;
    }
    LGK(0);
  }
}

// ---------------- output GEMM: [32768x1024] x [1024x1024]^T + bias -> fp32 --
__global__ __launch_bounds__(512, 2) void k_gemm_out(
    const u16* __restrict__ A, const u16* __restrict__ Bm,
    const float* __restrict__ bo, float* __restrict__ out) {
  __shared__ char lds[131072];
  const int tid = threadIdx.x;
  const int lane = tid & 63, w = tid >> 6;
  const int wr = w >> 2, wc = w & 3;
  const int l15 = lane & 15, l4 = lane >> 4;
  int f = blockIdx.x;  // 512 blocks = 8 chunks of 64, col-fastest
  int swz = (f & 7) * 64 + (f >> 3);
  int bcol = swz & 3, brow = swz >> 2;
  const int row0 = brow * 256, col0 = bcol * 256;
  f32x4 acc[8][4] = {};
  gemm256_core(A, Bm, row0, col0, lds, acc, tid);
  // ---- coalesced epilogue via LDS bounce ----
  char* eb = lds + w * 16384;
  const int colW = col0 + wc * 64;
  const float* biasW = bo + colW;
#pragma unroll
  for (int r = 0; r < 4; r++) {
#pragma unroll
    for (int mm = 0; mm < 2; mm++) {
      int mf = r * 2 + mm;
#pragma unroll
      for (int nf = 0; nf < 4; nf++)
#pragma unroll
        for (int j = 0; j < 4; j++) {
          int rowl = mm * 16 + l4 * 4 + j;
          *(float*)(eb + rowl * 272 + (nf * 16 + l15) * 4) = acc[mf][nf][j];
        }
    }
    LGK(0);
#pragma unroll
    for (int it = 0; it < 8; it++) {
      int u = it * 64 + lane;
      int rowl = u >> 4, ch = u & 15;
      float4 a0 = *(const float4*)(eb + rowl * 272 + ch * 16);
      float4 b0 = *(const float4*)(biasW + ch * 4);
      a0.x += b0.x; a0.y += b0.y; a0.z += b0.z; a0.w += b0.w;
      int row = row0 + wr * 128 + r * 32 + rowl;
      *(float4*)(out + (size_t)row * 1024 + colW + ch * 4) = a0;
    }
    LGK(0);
  }
}

// ---------------- bias1[b,h,t,s] = sum_d q[b,h,t,d]*rel_k[h,idx[t,s],d] + T3
__global__ __launch_bounds__(256) void k_bias1(
    const u16* __restrict__ Qb, const u16* __restrict__ relq,
    const u16* __restrict__ relk, const int* __restrict__ relidx,
    u16* __restrict__ bias1) {
  const int tid = threadIdx.x, lane = tid & 63, w = tid >> 6;
  const int l15 = lane & 15, l4 = lane >> 4;
  const int t = blockIdx.x, h = blockIdx.y, bc = blockIdx.z;
  __shared__ char lds[16640];
  char* RK = lds;
  char* RQ = lds + 8192;
  float* T3 = (float*)(lds + 16384);
#pragma unroll
  for (int c = 0; c < 2; c++) {
    int ch = c * 256 + tid;
    int sr = ch >> 3, sl = (ch & 7) ^ (sr & 7);
    int ri = relidx[t * 64 + sr];
    size_t so = ((size_t)h * 225 + ri) * 64 + sl * 8;
    g2l16(relk + so, RK + c * 4096 + w * 1024);
    g2l16(relq + so, RQ + c * 4096 + w * 1024);
  }
  __syncthreads();
  if (tid < 64) {
    int sr = tid;
    float sum = 0.f;
#pragma unroll
    for (int sl = 0; sl < 8; sl++) {
      int o = sr * 128 + ((sl ^ (sr & 7)) << 4);
      bf16x8 aq = *(const bf16x8*)(RQ + o);
      bf16x8 ak = *(const bf16x8*)(RK + o);
#pragma unroll
      for (int j = 0; j < 8; j++) sum += (float)aq[j] * (float)ak[j];
    }
    T3[sr] = sum;
  }
  bf16x8 bfr[4][2];
#pragma unroll
  for (int n = 0; n < 4; n++)
#pragma unroll
    for (int kh = 0; kh < 2; kh++) {
      int r = n * 16 + l15;
      int sl = ((kh << 2) + l4) ^ (r & 7);
      bfr[n][kh] = *(const bf16x8*)(RK + r * 128 + sl * 16);
    }
  __syncthreads();
  f32x4 acc[4][4] = {};
#pragma unroll
  for (int m = 0; m < 4; m++) {
    int bb = bc * 256 + w * 64 + m * 16 + l15;
    const u16* ap = Qb + ((size_t)(bb * 16 + h)) * 4096 + t * 64 + l4 * 8;
    bf16x8 a0 = *(const bf16x8*)ap;
    bf16x8 a1 = *(const bf16x8*)(ap + 32);
#pragma unroll
    for (int n = 0; n < 4; n++) {
      acc[m][n] = MFMA16(a0, bfr[n][0], acc[m][n]);
      acc[m][n] = MFMA16(a1, bfr[n][1], acc[m][n]);
    }
  }
#pragma unroll
  for (int m = 0; m < 4; m++)
#pragma unroll
    for (int n = 0; n < 4; n++)
#pragma unroll
      for (int j = 0; j < 4; j++) {
        int bb = bc * 256 + w * 64 + m * 16 + l4 * 4 + j;
        int s_ = n * 16 + l15;
        bias1[((size_t)(bb * 16 + h)) * 4096 + t * 64 + s_] =
            f2bf(acc[m][n][j] + T3[s_]);
      }
}

// ---------------- bias2[b,h,s,t] = sum_d rel_q[h,idx[t,s],d]*k[b,h,s,d]
__global__ __launch_bounds__(256) void k_bias2(
    const u16* __restrict__ Kb, const u16* __restrict__ relq,
    const int* __restrict__ relidx, u16* __restrict__ bias2) {
  const int tid = threadIdx.x, lane = tid & 63, w = tid >> 6;
  const int l15 = lane & 15, l4 = lane >> 4;
  const int s = blockIdx.x, h = blockIdx.y, bc = blockIdx.z;
  __shared__ char lds[8192];
#pragma unroll
  for (int c = 0; c < 2; c++) {
    int ch = c * 256 + tid;
    int tq = ch >> 3, sl = (ch & 7) ^ (tq & 7);
    int ri = relidx[tq * 64 + s];
    g2l16(relq + ((size_t)h * 225 + ri) * 64 + sl * 8,
          lds + c * 4096 + w * 1024);
  }
  __syncthreads();
  bf16x8 bfr[4][2];
#pragma unroll
  for (int n = 0; n < 4; n++)
#pragma unroll
    for (int kh = 0; kh < 2; kh++) {
      int r = n * 16 + l15;
      int sl = ((kh << 2) + l4) ^ (r & 7);
      bfr[n][kh] = *(const bf16x8*)(lds + r * 128 + sl * 16);
    }
  f32x4 acc[4][4] = {};
#pragma unroll
  for (int m = 0; m < 4; m++) {
    int bb = bc * 256 + w * 64 + m * 16 + l15;
    const u16* ap = Kb + ((size_t)(bb * 16 + h)) * 4096 + s * 64 + l4 * 8;
    bf16x8 a0 = *(const bf16x8*)ap;
    bf16x8 a1 = *(const bf16x8*)(ap + 32);
#pragma unroll
    for (int n = 0; n < 4; n++) {
      acc[m][n] = MFMA16(a0, bfr[n][0], acc[m][n]);
      acc[m][n] = MFMA16(a1, bfr[n][1], acc[m][n]);
    }
  }
#pragma unroll
  for (int m = 0; m < 4; m++)
#pragma unroll
    for (int n = 0; n < 4; n++)
#pragma unroll
      for (int j = 0; j < 4; j++) {
        int bb = bc * 256 + w * 64 + m * 16 + l4 * 4 + j;
        int tcol = n * 16 + l15;
        bias2[((size_t)(bb * 16 + h)) * 4096 + s * 64 + tcol] =
            f2bf(acc[m][n][j]);
      }
}

// ---------------- attention per (b,h): S=QK^T + b1 + b2^T, softmax, P, PV ----
__global__ __launch_bounds__(256) void k_attn(
    const u16* __restrict__ Qb, const u16* __restrict__ Kb,
    const u16* __restrict__ Vb, const u16* __restrict__ b1g,
    const u16* __restrict__ b2g, u16* __restrict__ Pg,
    u16* __restrict__ aout) {
  const int tid = threadIdx.x, lane = tid & 63, w = tid >> 6;
  const int l15 = lane & 15, l4 = lane >> 4;
  const int b = blockIdx.x, h = blockIdx.y;
  __shared__ char lds[49152];
  char* Qt = lds;
  char* Kt = lds + 8192;
  char* Vt = lds + 16384;  // natural [s][d] layout
  char* B1 = lds + 24576;
  char* B2 = lds + 32768;
  char* Pt = lds + 40960;
  const size_t base = ((size_t)(b * 16 + h)) * 4096;
#pragma unroll
  for (int c = 0; c < 2; c++) {
    int ch = c * 256 + tid;
    int r = ch >> 3, sl = (ch & 7) ^ (r & 7);
    size_t so = base + r * 64 + sl * 8;
    int dst = c * 4096 + w * 1024;
    g2l16(Qb + so, Qt + dst);
    g2l16(Kb + so, Kt + dst);
    g2l16(Vb + so, Vt + dst);
    g2l16(b1g + so, B1 + dst);
    g2l16(b2g + so, B2 + dst);
  }
  __syncthreads();
  // S = Q K^T, wave w owns rows [w*16, w*16+16)
  f32x4 acc[4] = {};
  bf16x8 qf[2];
  {
    int r = w * 16 + l15;
#pragma unroll
    for (int kh = 0; kh < 2; kh++) {
      int sl = ((kh << 2) + l4) ^ (r & 7);
      qf[kh] = *(const bf16x8*)(Qt + r * 128 + sl * 16);
    }
  }
#pragma unroll
  for (int n = 0; n < 4; n++) {
    int r = n * 16 + l15;
#pragma unroll
    for (int kh = 0; kh < 2; kh++) {
      int sl = ((kh << 2) + l4) ^ (r & 7);
      bf16x8 kf = *(const bf16x8*)(Kt + r * 128 + sl * 16);
      acc[n] = MFMA16(qf[kh], kf, acc[n]);
    }
  }
  const int t0 = w * 16 + l4 * 4;
#pragma unroll
  for (int j = 0; j < 4; j++) {
    int t_ = t0 + j;
    float lv[4];
#pragma unroll
    for (int n = 0; n < 4; n++) {
      int s_ = n * 16 + l15;
      float x = acc[n][j];
      x += bf2f(*(const u16*)(B1 + t_ * 128 + ((s_ * 2) ^ ((t_ & 7) << 4))));
      x += bf2f(*(const u16*)(B2 + s_ * 128 + ((t_ * 2) ^ ((s_ & 7) << 4))));
      lv[n] = x * 0.125f;
    }
    float mx = fmaxf(fmaxf(lv[0], lv[1]), fmaxf(lv[2], lv[3]));
#pragma unroll
    for (int d = 1; d < 16; d <<= 1) mx = fmaxf(mx, __shfl_xor(mx, d, 64));
    float e0 = __expf(lv[0] - mx), e1 = __expf(lv[1] - mx);
    float e2 = __expf(lv[2] - mx), e3 = __expf(lv[3] - mx);
    float sum = e0 + e1 + e2 + e3;
#pragma unroll
    for (int d = 1; d < 16; d <<= 1) sum += __shfl_xor(sum, d, 64);
    float inv = 1.0f / sum;
    float pe[4] = {e0 * inv, e1 * inv, e2 * inv, e3 * inv};
#pragma unroll
    for (int n = 0; n < 4; n++) {
      int s_ = n * 16 + l15;
      *(u16*)(Pt + t_ * 128 + ((s_ * 2) ^ ((t_ & 7) << 4))) = f2bf(pe[n]);
    }
  }
  __syncthreads();
  // P -> global (linearized, undo swizzle)
#pragma unroll
  for (int c = 0; c < 2; c++) {
    int ch = c * 256 + tid;
    int r = ch >> 3, sl = ch & 7;
    uint4 v = *(const uint4*)(Pt + r * 128 + ((sl ^ (r & 7)) << 4));
    *((uint4*)(Pg + base) + ch) = v;
  }
  // out_v = P * V; V is [s][d] -> B-frags via scalar column gather
  f32x4 acc2[4] = {};
  bf16x8 pf[2];
  {
    int r = w * 16 + l15;
#pragma unroll
    for (int kh = 0; kh < 2; kh++) {
      int sl = ((kh << 2) + l4) ^ (r & 7);
      pf[kh] = *(const bf16x8*)(Pt + r * 128 + sl * 16);
    }
  }
#pragma unroll
  for (int n = 0; n < 4; n++) {
#pragma unroll
    for (int kh = 0; kh < 2; kh++) {
      bf16x8 tmp;
#pragma unroll
      for (int j = 0; j < 8; j++) {
        int s_ = (kh << 5) + (l4 << 3) + j;
        int d_ = n * 16 + l15;
        u16 uu = *(const u16*)(Vt + s_ * 128 + ((d_ * 2) ^ ((s_ & 7) << 4)));
        tmp[j] = __builtin_bit_cast(__bf16, uu);
      }
      acc2[n] = MFMA16(pf[kh], tmp, acc2[n]);
    }
  }
#pragma unroll
  for (int n = 0; n < 4; n++)
#pragma unroll
    for (int j = 0; j < 4; j++) {
      int t_ = t0 + j, d_ = n * 16 + l15;
      aout[((size_t)(b * 64 + t_)) * 1024 + h * 64 + d_] = f2bf(acc2[n][j]);
    }
}

// ---------------- out_relv: aout[b,t,h,d] += sum_s P[b,s]*rel_v[h,idx[t,s],d]
__global__ __launch_bounds__(256) void k_relv(
    const u16* __restrict__ Pg, const u16* __restrict__ relv,
    const int* __restrict__ relidx, u16* __restrict__ aout) {
  const int tid = threadIdx.x, lane = tid & 63, w = tid >> 6;
  const int l15 = lane & 15, l4 = lane >> 4;
  const int t = blockIdx.x, h = blockIdx.y, bc = blockIdx.z;
  __shared__ char lds[8192];
#pragma unroll
  for (int c = 0; c < 2; c++) {
    int ch = c * 256 + tid;
    int sr = ch >> 3, sl = (ch & 7) ^ (sr & 7);
    int ri = relidx[t * 64 + sr];
    g2l16(relv + ((size_t)h * 225 + ri) * 64 + sl * 8,
          lds + c * 4096 + w * 1024);
  }
  __syncthreads();
  bf16x8 bfr[4][2];
#pragma unroll
  for (int n = 0; n < 4; n++)
#pragma unroll
    for (int kh = 0; kh < 2; kh++) {
      bf16x8 tmp;
#pragma unroll
      for (int j = 0; j < 8; j++) {
        int s_ = (kh << 5) + (l4 << 3) + j;
        int d_ = n * 16 + l15;
        u16 u = *(const u16*)(lds + s_ * 128 + ((d_ * 2) ^ ((s_ & 7) << 4)));
        tmp[j] = __builtin_bit_cast(__bf16, u);
      }
      bfr[n][kh] = tmp;
    }
  f32x4 acc[4][4] = {};
#pragma unroll
  for (int m = 0; m < 4; m++) {
    int bb = bc * 256 + w * 64 + m * 16 + l15;
    const u16* ap = Pg + ((size_t)(bb * 16 + h)) * 4096 + t * 64 + l4 * 8;
    bf16x8 a0 = *(const bf16x8*)ap;
    bf16x8 a1 = *(const bf16x8*)(ap + 32);
#pragma unroll
    for (int n = 0; n < 4; n++) {
      acc[m][n] = MFMA16(a0, bfr[n][0], acc[m][n]);
      acc[m][n] = MFMA16(a1, bfr[n][1], acc[m][n]);
    }
  }
#pragma unroll
  for (int m = 0; m < 4; m++)
#pragma unroll
    for (int n = 0; n < 4; n++)
#pragma unroll
      for (int j = 0; j < 4; j++) {
        int bb = bc * 256 + w * 64 + m * 16 + l4 * 4 + j;
        int d_ = n * 16 + l15;
        size_t o = ((size_t)(bb * 64 + t)) * 1024 + h * 64 + d_;
        aout[o] = f2bf(bf2f(aout[o]) + acc[m][n][j]);
      }
}

extern "C" void kernel_launch(void* const* d_in, const int* in_sizes, int n_in,
                              void* d_out, int out_size, void* d_ws,
                              size_t ws_size, hipStream_t stream) {
  const float* x = (const float*)d_in[0];
  const float* Wq = (const float*)d_in[1];
  const float* bq = (const float*)d_in[2];
  const float* Wk = (const float*)d_in[3];
  const float* bk = (const float*)d_in[4];
  const float* Wv = (const float*)d_in[5];
  const float* bv = (const float*)d_in[6];
  const float* Wo = (const float*)d_in[7];
  const float* bo = (const float*)d_in[8];
  const float* rq = (const float*)d_in[9];
  const float* rk = (const float*)d_in[10];
  const float* rv = (const float*)d_in[11];
  const int* ridx = (const int*)d_in[12];
  float* out = (float*)d_out;

  char* ws = (char*)d_ws;
  const size_t MB = 1ull << 20;
  u16* xb = (u16*)(ws + 0);  // reused as P after k_gemm_qkv consumes it
  u16* Qb = (u16*)(ws + 64 * MB);
  u16* Kb = (u16*)(ws + 128 * MB);
  u16* Vb = (u16*)(ws + 192 * MB);
  u16* b1 = (u16*)(ws + 256 * MB);
  u16* b2 = (u16*)(ws + 320 * MB);
  u16* aout = (u16*)(ws + 384 * MB);
  u16* wqkv = (u16*)(ws + 448 * MB);
  u16* wo = (u16*)(ws + 454 * MB);
  u16* relq = (u16*)(ws + 456 * MB);
  u16* relk = (u16*)(ws + 457 * MB);
  u16* relv = (u16*)(ws + 458 * MB);
  u16* Pg = xb;

  k_cvt<<<32768, 256, 0, stream>>>(x, xb, 8388608);
  k_cvt<<<1024, 256, 0, stream>>>(Wq, wqkv, 262144);
  k_cvt<<<1024, 256, 0, stream>>>(Wk, wqkv + 1048576, 262144);
  k_cvt<<<1024, 256, 0, stream>>>(Wv, wqkv + 2097152, 262144);
  k_cvt<<<1024, 256, 0, stream>>>(Wo, wo, 262144);
  k_cvt<<<225, 256, 0, stream>>>(rq, relq, 57600);
  k_cvt<<<225, 256, 0, stream>>>(rk, relk, 57600);
  k_cvt<<<225, 256, 0, stream>>>(rv, relv, 57600);

  k_gemm_qkv<<<1536, 512, 0, stream>>>(xb, wqkv, bq, bk, bv, Qb, Kb, Vb);
  k_bias1<<<dim3(64, 16, 2), 256, 0, stream>>>(Qb, relq, relk, ridx, b1);
  k_bias2<<<dim3(64, 16, 2), 256, 0, stream>>>(Kb, relq, ridx, b2);
  k_attn<<<dim3(512, 16), 256, 0, stream>>>(Qb, Kb, Vb, b1, b2, Pg, aout);
  k_relv<<<dim3(64, 16, 2), 256, 0, stream>>>(Pg, relv, ridx, aout);
  k_gemm_out<<<512, 512, 0, stream>>>(aout, wo, bo, out);
}